// Round 9
// baseline (312.219 us; speedup 1.0000x reference)
//
#include <hip/hip_runtime.h>
#include <hip/hip_fp16.h>

// ---------------------------------------------------------------------------
// OverAll graph-attention pipeline, MI355X (gfx950)
// N=40000 rows, R=2000 relations, T=500000 edges, D=128, DEPTH=2, DC=384
//
// Dataflow (fp16 planar staging, E-plane uints [0,64), R-plane [64,128)):
//   agg -> fsrc0 ; layer0 -> fsrc1 ;
//   layer1 -> scratch planes in d_out rows: E at uints [0,64), R at [704,768)
//   final_fused (ONE dispatch, both sides by blockIdx parity) -> d_out f32.
// Softmax: shift-free (scores bounded, exp(s) <= ~8e4, f32-safe).
//   relprep emits expS4[rel] = exp(score) for all 4 tables (float4, L2-hot);
//   stats4: one gather pass -> inv4[row] = 1/sum; layers compute
//   w = expS4[rel] * inv4[row] inline. No per-edge weight materialization.
// Layers: wave/row, 16-lane edge groups, FOUR edges per group in flight
// (16/wave), fdot2 dots, 8 interleaved reduce chains.
// Finals: 32 rows/block, 256 thr, f16 MFMA 32x32x16 (unchanged from R8).
// ---------------------------------------------------------------------------

typedef __attribute__((ext_vector_type(4))) float f32x4;
typedef _Float16 h16x2 __attribute__((ext_vector_type(2)));
typedef _Float16 f16x8 __attribute__((ext_vector_type(8)));
typedef float f32x16 __attribute__((ext_vector_type(16)));

__device__ __forceinline__ float wave_sum(float v) {
#pragma unroll
  for (int o = 32; o > 0; o >>= 1) v += __shfl_xor(v, o, 64);
  return v;
}
__device__ __forceinline__ float wave_max(float v) {
#pragma unroll
  for (int o = 32; o > 0; o >>= 1) v = fmaxf(v, __shfl_xor(v, o, 64));
  return v;
}
__device__ __forceinline__ unsigned pkhalf2(float a, float b) {
  __half2 h = __floats2half2_rn(a, b);
  return __builtin_bit_cast(unsigned, h);
}
__device__ __forceinline__ unsigned short f2h(float x) {
  return __builtin_bit_cast(unsigned short, (_Float16)x);
}
__device__ __forceinline__ float h2f(unsigned short h) {
  return (float)__builtin_bit_cast(_Float16, h);
}
__device__ __forceinline__ float tanh_fast(float x) {
  float t = __expf(-2.f * fabsf(x));
  float y = (1.f - t) / (1.f + t);
  return copysignf(y, x);
}
__device__ __forceinline__ float fdot2u(unsigned a, unsigned b, float c) {
#if __has_builtin(__builtin_amdgcn_fdot2)
  return __builtin_amdgcn_fdot2(__builtin_bit_cast(h16x2, a),
                                __builtin_bit_cast(h16x2, b), c, false);
#else
  h16x2 x = __builtin_bit_cast(h16x2, a), y = __builtin_bit_cast(h16x2, b);
  return fmaf((float)x.x, (float)y.x, fmaf((float)x.y, (float)y.y, c));
#endif
}
__device__ __forceinline__ float dot8(uint4 a, uint4 b) {
  return fdot2u(a.w, b.w, fdot2u(a.z, b.z, fdot2u(a.y, b.y,
         fdot2u(a.x, b.x, 0.f))));
}

// ---------------------------------------------------------------------------
__global__ void rowptr3_kernel(const int* __restrict__ e0,
                               const int* __restrict__ e1,
                               const int* __restrict__ e2, int T, int N,
                               int* __restrict__ p0, int* __restrict__ p1,
                               int* __restrict__ p2) {
  int tid = blockIdx.x * blockDim.x + threadIdx.x;
  int which = tid / (N + 1);
  int r = tid - which * (N + 1);
  if (which >= 3) return;
  const int* E = which == 0 ? e0 : (which == 1 ? e1 : e2);
  int* P = which == 0 ? p0 : (which == 1 ? p1 : p2);
  int lo = 0, hi = T;
  while (lo < hi) {
    int mid = (lo + hi) >> 1;
    if (E[2 * mid] < r) lo = mid + 1; else hi = mid;
  }
  P[r] = lo;
}

// Per relation: fp16 normalized vec + fp16 raw vec + exp(score) float4 table.
__global__ void relprep_kernel(const float* __restrict__ rel_emb,
                               const float* __restrict__ e_attn,
                               const float* __restrict__ r_attn, int R,
                               float4* __restrict__ expS4,
                               unsigned* __restrict__ rnorm,
                               unsigned* __restrict__ rel16) {
  int r = blockIdx.x * 4 + (threadIdx.x >> 6);
  int lane = threadIdx.x & 63;
  if (r >= R) return;
  float2 v  = *(const float2*)(rel_emb + (size_t)r * 128 + 2 * lane);
  float2 a0 = *(const float2*)(e_attn + 2 * lane);
  float2 a1 = *(const float2*)(e_attn + 128 + 2 * lane);
  float2 b0 = *(const float2*)(r_attn + 2 * lane);
  float2 b1 = *(const float2*)(r_attn + 128 + 2 * lane);
  float n  = wave_sum(v.x * v.x + v.y * v.y);
  float d0 = wave_sum(v.x * a0.x + v.y * a0.y);
  float d1 = wave_sum(v.x * a1.x + v.y * a1.y);
  float d2 = wave_sum(v.x * b0.x + v.y * b0.y);
  float d3 = wave_sum(v.x * b1.x + v.y * b1.y);
  float inv = 1.f / fmaxf(sqrtf(n), 1e-12f);
  rnorm[(size_t)r * 64 + lane] = pkhalf2(v.x * inv, v.y * inv);
  rel16[(size_t)r * 64 + lane] = pkhalf2(v.x, v.y);
  if (lane == 0) {
    // tables: x = E/layer0, y = E/layer1, z = R/layer0, w = R/layer1
    expS4[r] = make_float4(__expf(d0 * inv), __expf(d1 * inv),
                           __expf(d2 * inv), __expf(d3 * inv));
  }
}

__global__ void pack_f16_kernel(const float* __restrict__ src,
                                unsigned* __restrict__ dst, int n2) {
  int i = blockIdx.x * blockDim.x + threadIdx.x;
  if (i >= n2) return;
  float2 v = *(const float2*)(src + 2 * (size_t)i);
  dst[i] = pkhalf2(v.x, v.y);
}

// pk[e] = col | rel<<16  (col < 65536, rel < 65536)
__global__ void pack_edges_kernel(const int* __restrict__ adj,
                                  const int* __restrict__ idx,
                                  unsigned* __restrict__ pk, int T) {
  int e = blockIdx.x * blockDim.x + threadIdx.x;
  if (e >= T) return;
  pk[e] = (unsigned)adj[2 * e + 1] | ((unsigned)idx[2 * e + 1] << 16);
}

// Shift-free softmax denominators for all 4 tables: inv4[r] = 1/sum(expS)
__global__ __launch_bounds__(256) void stats4_kernel(
    const int* __restrict__ ptr, const unsigned* __restrict__ pk,
    const float4* __restrict__ expS4, float4* __restrict__ inv4, int N) {
  int r = blockIdx.x * 4 + (threadIdx.x >> 6);
  if (r >= N) return;
  int lane = threadIdx.x & 63;
  int beg = ptr[r], end = ptr[r + 1];
  float d0 = 0.f, d1 = 0.f, d2 = 0.f, d3 = 0.f;
  for (int e = beg + lane; e < end; e += 64) {
    float4 es = expS4[pk[e] >> 16];
    d0 += es.x; d1 += es.y; d2 += es.z; d3 += es.w;
  }
#pragma unroll
  for (int o = 32; o > 0; o >>= 1) {
    d0 += __shfl_xor(d0, o, 64); d1 += __shfl_xor(d1, o, 64);
    d2 += __shfl_xor(d2, o, 64); d3 += __shfl_xor(d3, o, 64);
  }
  if (lane == 0) {
    inv4[r] = make_float4(d0 > 0.f ? 1.f / d0 : 0.f,
                          d1 > 0.f ? 1.f / d1 : 0.f,
                          d2 > 0.f ? 1.f / d2 : 0.f,
                          d3 > 0.f ? 1.f / d3 : 0.f);
  }
}

// ---------------------------------------------------------------------------
// Fused agg (e+r): wave/row, 16-lane groups, FOUR edges per group in flight.
__global__ __launch_bounds__(256) void agg_fused_kernel(
    const int* __restrict__ ptrE, const int* __restrict__ edgesE,
    const unsigned* __restrict__ ent16, const int* __restrict__ ptrR,
    const int* __restrict__ edgesR, const unsigned* __restrict__ rel16,
    unsigned* __restrict__ fout, int N) {
  int r = blockIdx.x * 4 + (threadIdx.x >> 6);
  if (r >= N) return;
  int lane = threadIdx.x & 63;
  int g = lane >> 4, q = lane & 15;

  float aE[8] = {0, 0, 0, 0, 0, 0, 0, 0};
  float aR[8] = {0, 0, 0, 0, 0, 0, 0, 0};

  auto addh = [&](uint4 u, float* a) {
    h16x2 h0 = __builtin_bit_cast(h16x2, u.x), h1 = __builtin_bit_cast(h16x2, u.y);
    h16x2 h2 = __builtin_bit_cast(h16x2, u.z), h3 = __builtin_bit_cast(h16x2, u.w);
    a[0] += (float)h0.x; a[1] += (float)h0.y;
    a[2] += (float)h1.x; a[3] += (float)h1.y;
    a[4] += (float)h2.x; a[5] += (float)h2.y;
    a[6] += (float)h3.x; a[7] += (float)h3.y;
  };

  int begE = ptrE[r], endE = ptrE[r + 1];
  for (int e0 = begE; e0 < endE; e0 += 16) {
    int eA = e0 + g, eB = eA + 4, eC = eA + 8, eD = eA + 12;
    if (eA < endE)
      addh(*(const uint4*)(ent16 + (size_t)edgesE[2 * eA + 1] * 64 + 4 * q), aE);
    if (eB < endE)
      addh(*(const uint4*)(ent16 + (size_t)edgesE[2 * eB + 1] * 64 + 4 * q), aE);
    if (eC < endE)
      addh(*(const uint4*)(ent16 + (size_t)edgesE[2 * eC + 1] * 64 + 4 * q), aE);
    if (eD < endE)
      addh(*(const uint4*)(ent16 + (size_t)edgesE[2 * eD + 1] * 64 + 4 * q), aE);
  }
  int begR = ptrR[r], endR = ptrR[r + 1];
  for (int e0 = begR; e0 < endR; e0 += 16) {
    int eA = e0 + g, eB = eA + 4, eC = eA + 8, eD = eA + 12;
    if (eA < endR)
      addh(*(const uint4*)(rel16 + (size_t)edgesR[2 * eA + 1] * 64 + 4 * q), aR);
    if (eB < endR)
      addh(*(const uint4*)(rel16 + (size_t)edgesR[2 * eB + 1] * 64 + 4 * q), aR);
    if (eC < endR)
      addh(*(const uint4*)(rel16 + (size_t)edgesR[2 * eC + 1] * 64 + 4 * q), aR);
    if (eD < endR)
      addh(*(const uint4*)(rel16 + (size_t)edgesR[2 * eD + 1] * 64 + 4 * q), aR);
  }
#pragma unroll
  for (int j = 0; j < 8; ++j) {
    aE[j] += __shfl_xor(aE[j], 16, 64); aE[j] += __shfl_xor(aE[j], 32, 64);
    aR[j] += __shfl_xor(aR[j], 16, 64); aR[j] += __shfl_xor(aR[j], 32, 64);
  }
  float sE = (endE > begE) ? 1.f / (float)(endE - begE) : 0.f;
  float sR = (endR > begR) ? 1.f / (float)(endR - begR) : 0.f;
  if (g == 0) {
    float t[8];
#pragma unroll
    for (int j = 0; j < 8; ++j) t[j] = tanh_fast(aE[j] * sE);
    uint4 u;
    u.x = pkhalf2(t[0], t[1]); u.y = pkhalf2(t[2], t[3]);
    u.z = pkhalf2(t[4], t[5]); u.w = pkhalf2(t[6], t[7]);
    *(uint4*)(fout + (size_t)r * 128 + 4 * q) = u;
  } else if (g == 1) {
    float t[8];
#pragma unroll
    for (int j = 0; j < 8; ++j) t[j] = tanh_fast(aR[j] * sR);
    uint4 u;
    u.x = pkhalf2(t[0], t[1]); u.y = pkhalf2(t[2], t[3]);
    u.z = pkhalf2(t[4], t[5]); u.w = pkhalf2(t[6], t[7]);
    *(uint4*)(fout + (size_t)r * 128 + 64 + 4 * q) = u;
  }
}

// ---------------------------------------------------------------------------
// Fused e+r layer: wave/row, 16-lane groups, FOUR edges per group in flight.
// Weights computed inline: w = expS4[rel].{sel} * inv4[row].{sel}.
__global__ __launch_bounds__(256) void layer_rec_kernel(
    const int* __restrict__ ptr, const unsigned* __restrict__ pk,
    const float4* __restrict__ expS4, const float4* __restrict__ inv4,
    const unsigned* __restrict__ rnorm, const unsigned* __restrict__ fin,
    unsigned* __restrict__ foutE, unsigned* __restrict__ foutR, int fstride,
    int N, int lay) {
  int r = blockIdx.x * 4 + (threadIdx.x >> 6);
  if (r >= N) return;
  int lane = threadIdx.x & 63;
  int g = lane >> 4, q = lane & 15;
  int beg = ptr[r], end = ptr[r + 1];
  float4 iv = inv4[r];
  float ivE = lay ? iv.y : iv.x;
  float ivR = lay ? iv.w : iv.z;

  float aE[8] = {0, 0, 0, 0, 0, 0, 0, 0};
  float aR[8] = {0, 0, 0, 0, 0, 0, 0, 0};

  auto accum = [&](uint4 F, uint4 V, float w, float s, float* a) {
    h16x2 f0 = __builtin_bit_cast(h16x2, F.x), v0 = __builtin_bit_cast(h16x2, V.x);
    h16x2 f1 = __builtin_bit_cast(h16x2, F.y), v1 = __builtin_bit_cast(h16x2, V.y);
    h16x2 f2 = __builtin_bit_cast(h16x2, F.z), v2 = __builtin_bit_cast(h16x2, V.z);
    h16x2 f3 = __builtin_bit_cast(h16x2, F.w), v3 = __builtin_bit_cast(h16x2, V.w);
    a[0] = fmaf((float)f0.x, w, fmaf((float)v0.x, s, a[0]));
    a[1] = fmaf((float)f0.y, w, fmaf((float)v0.y, s, a[1]));
    a[2] = fmaf((float)f1.x, w, fmaf((float)v1.x, s, a[2]));
    a[3] = fmaf((float)f1.y, w, fmaf((float)v1.y, s, a[3]));
    a[4] = fmaf((float)f2.x, w, fmaf((float)v2.x, s, a[4]));
    a[5] = fmaf((float)f2.y, w, fmaf((float)v2.y, s, a[5]));
    a[6] = fmaf((float)f3.x, w, fmaf((float)v3.x, s, a[6]));
    a[7] = fmaf((float)f3.y, w, fmaf((float)v3.y, s, a[7]));
  };

  for (int e0 = beg; e0 < end; e0 += 16) {
    int eA = e0 + g, eB = eA + 4, eC = eA + 8, eD = eA + 12;
    bool cA = eA < end, cB = eB < end, cC = eC < end, cD = eD < end;
    unsigned pA = cA ? pk[eA] : 0u, pB = cB ? pk[eB] : 0u;
    unsigned pC = cC ? pk[eC] : 0u, pD = cD ? pk[eD] : 0u;
    int colA = (int)(pA & 0xFFFFu), relA = (int)(pA >> 16);
    int colB = (int)(pB & 0xFFFFu), relB = (int)(pB >> 16);
    int colC = (int)(pC & 0xFFFFu), relC = (int)(pC >> 16);
    int colD = (int)(pD & 0xFFFFu), relD = (int)(pD >> 16);

    const unsigned* fA = fin + (size_t)colA * 128;
    const unsigned* fB = fin + (size_t)colB * 128;
    const unsigned* fC = fin + (size_t)colC * 128;
    const unsigned* fD = fin + (size_t)colD * 128;
    uint4 EA = *(const uint4*)(fA + 4 * q);
    uint4 RA = *(const uint4*)(fA + 64 + 4 * q);
    uint4 VA = *(const uint4*)(rnorm + (size_t)relA * 64 + 4 * q);
    uint4 EB = *(const uint4*)(fB + 4 * q);
    uint4 RB = *(const uint4*)(fB + 64 + 4 * q);
    uint4 VB = *(const uint4*)(rnorm + (size_t)relB * 64 + 4 * q);
    uint4 EC = *(const uint4*)(fC + 4 * q);
    uint4 RC = *(const uint4*)(fC + 64 + 4 * q);
    uint4 VC = *(const uint4*)(rnorm + (size_t)relC * 64 + 4 * q);
    uint4 ED = *(const uint4*)(fD + 4 * q);
    uint4 RD = *(const uint4*)(fD + 64 + 4 * q);
    uint4 VD = *(const uint4*)(rnorm + (size_t)relD * 64 + 4 * q);

    float dAE = dot8(EA, VA), dAR = dot8(RA, VA);
    float dBE = dot8(EB, VB), dBR = dot8(RB, VB);
    float dCE = dot8(EC, VC), dCR = dot8(RC, VC);
    float dDE = dot8(ED, VD), dDR = dot8(RD, VD);
#pragma unroll
    for (int m = 1; m < 16; m <<= 1) {
      dAE += __shfl_xor(dAE, m, 64); dAR += __shfl_xor(dAR, m, 64);
      dBE += __shfl_xor(dBE, m, 64); dBR += __shfl_xor(dBR, m, 64);
      dCE += __shfl_xor(dCE, m, 64); dCR += __shfl_xor(dCR, m, 64);
      dDE += __shfl_xor(dDE, m, 64); dDR += __shfl_xor(dDR, m, 64);
    }

    float4 esA = cA ? expS4[relA] : make_float4(0, 0, 0, 0);
    float4 esB = cB ? expS4[relB] : make_float4(0, 0, 0, 0);
    float4 esC = cC ? expS4[relC] : make_float4(0, 0, 0, 0);
    float4 esD = cD ? expS4[relD] : make_float4(0, 0, 0, 0);
    float wAE = (lay ? esA.y : esA.x) * ivE, wAR = (lay ? esA.w : esA.z) * ivR;
    float wBE = (lay ? esB.y : esB.x) * ivE, wBR = (lay ? esB.w : esB.z) * ivR;
    float wCE = (lay ? esC.y : esC.x) * ivE, wCR = (lay ? esC.w : esC.z) * ivR;
    float wDE = (lay ? esD.y : esD.x) * ivE, wDR = (lay ? esD.w : esD.z) * ivR;

    accum(EA, VA, wAE, -2.f * wAE * dAE, aE);
    accum(RA, VA, wAR, -2.f * wAR * dAR, aR);
    accum(EB, VB, wBE, -2.f * wBE * dBE, aE);
    accum(RB, VB, wBR, -2.f * wBR * dBR, aR);
    accum(EC, VC, wCE, -2.f * wCE * dCE, aE);
    accum(RC, VC, wCR, -2.f * wCR * dCR, aR);
    accum(ED, VD, wDE, -2.f * wDE * dDE, aE);
    accum(RD, VD, wDR, -2.f * wDR * dDR, aR);
  }

#pragma unroll
  for (int j = 0; j < 8; ++j) {
    aE[j] += __shfl_xor(aE[j], 16, 64); aE[j] += __shfl_xor(aE[j], 32, 64);
    aR[j] += __shfl_xor(aR[j], 16, 64); aR[j] += __shfl_xor(aR[j], 32, 64);
  }
  if (g == 0) {
    float t[8];
#pragma unroll
    for (int j = 0; j < 8; ++j) t[j] = tanh_fast(aE[j]);
    uint4 u;
    u.x = pkhalf2(t[0], t[1]); u.y = pkhalf2(t[2], t[3]);
    u.z = pkhalf2(t[4], t[5]); u.w = pkhalf2(t[6], t[7]);
    *(uint4*)(foutE + (size_t)r * fstride + 4 * q) = u;
  } else if (g == 1) {
    float t[8];
#pragma unroll
    for (int j = 0; j < 8; ++j) t[j] = tanh_fast(aR[j]);
    uint4 u;
    u.x = pkhalf2(t[0], t[1]); u.y = pkhalf2(t[2], t[3]);
    u.z = pkhalf2(t[4], t[5]); u.w = pkhalf2(t[6], t[7]);
    *(uint4*)(foutR + (size_t)r * fstride + 4 * q) = u;
  }
}

// ---------------------------------------------------------------------------
// Pack B matrices into f16 MFMA 32x32x16 fragment order.
__device__ __forceinline__ void pack_one32(const float* __restrict__ src,
                                           unsigned short* __restrict__ dst,
                                           int NT, int srcld, int mode, int f,
                                           int lane) {
  int kt = f / NT, nt = f % NT;
  int kbase = 16 * kt + 8 * (lane >> 5);
  int n = 32 * nt + (lane & 31);
  unsigned short tmp[8];
#pragma unroll
  for (int j = 0; j < 8; ++j) {
    int k = kbase + j;
    float v = (mode == 0) ? src[(size_t)k * srcld + n] : src[(size_t)n * srcld + k];
    tmp[j] = f2h(v);
  }
  *(uint4*)(dst + ((size_t)f * 64 + lane) * 8) = *(uint4*)tmp;
}
__global__ void pack_all_kernel(const float* eP, const float* eG,
                                const float* rP, const float* rG,
                                unsigned short* b1e, unsigned short* b2e,
                                unsigned short* b3e, unsigned short* b1r,
                                unsigned short* b2r, unsigned short* b3r) {
  int f = blockIdx.x * 4 + (threadIdx.x >> 6);
  int lane = threadIdx.x & 63;
  if (f < 48)       pack_one32(eP, b1e, 2, 384, 1, f, lane);
  else if (f < 96)  pack_one32(eP, b2e, 12, 384, 0, f - 48, lane);
  else if (f < 384) pack_one32(eG, b3e, 12, 384, 0, f - 96, lane);
  else if (f < 432) pack_one32(rP, b1r, 2, 384, 1, f - 384, lane);
  else if (f < 480) pack_one32(rP, b2r, 12, 384, 0, f - 432, lane);
  else if (f < 768) pack_one32(rG, b3r, 12, 384, 0, f - 480, lane);
}

// ---------------------------------------------------------------------------
// Fused proxy/gate epilogue: both sides in one dispatch (side = blockIdx&1).
// 32 rows/block, 256 threads (4 waves), f16 MFMA 32x32x16.
// C/D layout: col = lane&31, row = (reg&3) + 8*(reg>>2) + 4*(lane>>5).
__global__ __launch_bounds__(256) void final_fused_kernel(
    const unsigned* __restrict__ f0, const unsigned* __restrict__ f1,
    const unsigned* __restrict__ outu,
    const unsigned short* __restrict__ B1e, const unsigned short* __restrict__ B2e,
    const unsigned short* __restrict__ B3e, const unsigned short* __restrict__ B1r,
    const unsigned short* __restrict__ B2r, const unsigned short* __restrict__ B3r,
    const float* __restrict__ biasE, const float* __restrict__ biasR,
    float* __restrict__ gout) {
  __shared__ __align__(16) unsigned sOutH[32][204];   // fp16 pairs (192 used)
  __shared__ __align__(16) float sPa[32][68];
  __shared__ __align__(16) unsigned short sPaH[32][72];
  __shared__ float sInv[32];
  unsigned short* sOutHs = (unsigned short*)&sOutH[0][0];  // row stride 408

  const int side = blockIdx.x & 1;
  const int row0 = (blockIdx.x >> 1) * 32;
  const int plane = side ? 64 : 0;
  const unsigned* f2 = outu + (side ? 704 : 0);
  const unsigned short* B1 = side ? B1r : B1e;
  const unsigned short* B2 = side ? B2r : B2e;
  const unsigned short* B3 = side ? B3r : B3e;
  const float* bias = side ? biasR : biasE;
  const int coloff = side ? 384 : 0;

  const int t = threadIdx.x;
  const int w = t >> 6, lane = t & 63;
  const int l31 = lane & 31, l5 = lane >> 5;

  // 1. load outputs planes + fused row sumsq (8 threads per row)
  {
    int rloc = t >> 3;      // 0..31
    int c0 = t & 7;
    int rg = row0 + rloc;
    float ss = 0.f;
#pragma unroll
    for (int i = 0; i < 6; ++i) {
      int c = c0 + 8 * i;   // 0..47
      int buf = c >> 4, j = c & 15;
      const unsigned* src;
      if (buf == 0)      src = f0 + (size_t)rg * 128 + plane + 4 * j;
      else if (buf == 1) src = f1 + (size_t)rg * 128 + plane + 4 * j;
      else               src = f2 + (size_t)rg * 768 + 4 * j;
      uint4 u = *(const uint4*)src;
      *(uint4*)&sOutH[rloc][c * 4] = u;
      ss = fdot2u(u.x, u.x, fdot2u(u.y, u.y,
           fdot2u(u.z, u.z, fdot2u(u.w, u.w, ss))));
    }
    ss += __shfl_xor(ss, 1, 64);
    ss += __shfl_xor(ss, 2, 64);
    ss += __shfl_xor(ss, 4, 64);
    if (c0 == 0) sInv[rloc] = 1.f / fmaxf(sqrtf(ss), 1e-12f);
  }
  __syncthreads();

  // 2. GEMM1: S = outputs @ proxyT (waves 0,1; ct = w)
  if (w < 2) {
    int ct = w;
    f32x16 acc = {0.f, 0.f, 0.f, 0.f, 0.f, 0.f, 0.f, 0.f,
                  0.f, 0.f, 0.f, 0.f, 0.f, 0.f, 0.f, 0.f};
#pragma unroll
    for (int kt = 0; kt < 24; ++kt) {
      f16x8 a = __builtin_bit_cast(
          f16x8, *(const uint4*)&sOutH[l31][8 * kt + 4 * l5]);
      f16x8 b = *(const f16x8*)(B1 + ((size_t)(kt * 2 + ct) * 64 + lane) * 8);
      acc = __builtin_amdgcn_mfma_f32_32x32x16_f16(a, b, acc, 0, 0, 0);
    }
#pragma unroll
    for (int reg = 0; reg < 16; ++reg) {
      int row = (reg & 3) + 8 * (reg >> 2) + 4 * l5;
      sPa[row][ct * 32 + l31] = acc[reg] * sInv[row];
    }
  }
  __syncthreads();

  // 3. softmax over 64 proxies (8 rows/wave) -> f16 pa
  for (int rr = 8 * w; rr < 8 * w + 8; ++rr) {
    float v = sPa[rr][lane];
    float mx = wave_max(v);
    float e = __expf(v - mx);
    float s = wave_sum(e);
    sPaH[rr][lane] = f2h(e / s);
  }
  __syncthreads();

  // 4. GEMM2: pf = outputs - pa @ proxy; overwrite sOutH with pf,
  //    stash outputs bits in regs. wave w -> strips 3w..3w+2
  const int ntb = 3 * w;
  unsigned outv[3][8];
  {
    f32x16 acc2[3];
#pragma unroll
    for (int s = 0; s < 3; ++s)
#pragma unroll
      for (int i = 0; i < 16; ++i) acc2[s][i] = 0.f;
#pragma unroll
    for (int kt = 0; kt < 4; ++kt) {
      f16x8 a = __builtin_bit_cast(
          f16x8, *(const uint4*)&sPaH[l31][16 * kt + 8 * l5]);
#pragma unroll
      for (int s = 0; s < 3; ++s) {
        f16x8 b = *(const f16x8*)(B2 + ((size_t)(kt * 12 + ntb + s) * 64 + lane) * 8);
        acc2[s] = __builtin_amdgcn_mfma_f32_32x32x16_f16(a, b, acc2[s], 0, 0, 0);
      }
    }
#pragma unroll
    for (int s = 0; s < 3; ++s) {
      int col = 32 * (ntb + s) + l31;
#pragma unroll
      for (int p = 0; p < 8; ++p) {
        int ra = ((2 * p) & 3) + 8 * (p >> 1) + 4 * l5;
        unsigned short u0 = sOutHs[ra * 408 + col];
        unsigned short u1 = sOutHs[(ra + 1) * 408 + col];
        outv[s][p] = (unsigned)u0 | ((unsigned)u1 << 16);
        float pf0 = h2f(u0) - acc2[s][2 * p];
        float pf1 = h2f(u1) - acc2[s][2 * p + 1];
        sOutHs[ra * 408 + col] = f2h(pf0);
        sOutHs[(ra + 1) * 408 + col] = f2h(pf1);
      }
    }
  }
  __syncthreads();

  // 5. GEMM3: gate logits = pf @ gateK (kt-outer, A reused across 3 strips)
  f32x16 acc3[3];
#pragma unroll
  for (int s = 0; s < 3; ++s)
#pragma unroll
    for (int i = 0; i < 16; ++i) acc3[s][i] = 0.f;
#pragma unroll
  for (int kt = 0; kt < 24; ++kt) {
    f16x8 a = __builtin_bit_cast(
        f16x8, *(const uint4*)&sOutH[l31][8 * kt + 4 * l5]);
#pragma unroll
    for (int s = 0; s < 3; ++s) {
      f16x8 b = *(const f16x8*)(B3 + ((size_t)(kt * 12 + ntb + s) * 64 + lane) * 8);
      acc3[s] = __builtin_amdgcn_mfma_f32_32x32x16_f16(a, b, acc3[s], 0, 0, 0);
    }
  }

  // 6. sigmoid gate + combine + store
#pragma unroll
  for (int s = 0; s < 3; ++s) {
    int col = 32 * (ntb + s) + l31;
    float bv = bias[col];
#pragma unroll
    for (int p = 0; p < 8; ++p) {
      int ra = ((2 * p) & 3) + 8 * (p >> 1) + 4 * l5;
      float g0 = 1.f / (1.f + __expf(-(acc3[s][2 * p] + bv)));
      float g1 = 1.f / (1.f + __expf(-(acc3[s][2 * p + 1] + bv)));
      float pf0 = h2f(sOutHs[ra * 408 + col]);
      float pf1 = h2f(sOutHs[(ra + 1) * 408 + col]);
      unsigned ov = outv[s][p];
      float o0 = h2f((unsigned short)(ov & 0xffffu));
      float o1 = h2f((unsigned short)(ov >> 16));
      gout[(size_t)(row0 + ra) * 768 + coloff + col] = g0 * o0 + (1.f - g0) * pf0;
      gout[(size_t)(row0 + ra + 1) * 768 + coloff + col] =
          g1 * o1 + (1.f - g1) * pf1;
    }
  }
}

extern "C" void kernel_launch(void* const* d_in, const int* in_sizes, int n_in,
                              void* d_out, int out_size, void* d_ws,
                              size_t ws_size, hipStream_t stream) {
  (void)n_in; (void)out_size; (void)ws_size;
  const float* ent_emb = (const float*)d_in[0];
  const float* rel_emb = (const float*)d_in[1];
  const float* e_gate  = (const float*)d_in[2];
  const float* e_proxy = (const float*)d_in[3];
  const float* e_bias  = (const float*)d_in[4];
  const float* e_attn  = (const float*)d_in[5];
  const float* r_gate  = (const float*)d_in[6];
  const float* r_proxy = (const float*)d_in[7];
  const float* r_bias  = (const float*)d_in[8];
  const float* r_attn  = (const float*)d_in[9];
  const int* adj   = (const int*)d_in[11];
  const int* idx   = (const int*)d_in[12];
  const int* ent_m = (const int*)d_in[13];
  const int* rel_m = (const int*)d_in[14];
  const int N = in_sizes[0] / 128;
  const int R = in_sizes[1] / 128;
  const int T = in_sizes[10];
  float* out = (float*)d_out;

  char* w = (char*)d_ws;
  size_t used = 0;
  auto alloc = [&](size_t bytes) {
    void* p = (void*)(w + used);
    used += (bytes + 255) & ~(size_t)255;
    return p;
  };
  int* ptr_adj  = (int*)alloc((size_t)(N + 1) * sizeof(int));
  int* ptr_ent  = (int*)alloc((size_t)(N + 1) * sizeof(int));
  int* ptr_rel  = (int*)alloc((size_t)(N + 1) * sizeof(int));
  unsigned short* b1e = (unsigned short*)alloc(48 * 1024);
  unsigned short* b2e = (unsigned short*)alloc(48 * 1024);
  unsigned short* b3e = (unsigned short*)alloc(288 * 1024);
  unsigned short* b1r = (unsigned short*)alloc(48 * 1024);
  unsigned short* b2r = (unsigned short*)alloc(48 * 1024);
  unsigned short* b3r = (unsigned short*)alloc(288 * 1024);
  unsigned* rnorm = (unsigned*)alloc((size_t)R * 64 * 4);
  unsigned* rel16 = (unsigned*)alloc((size_t)R * 64 * 4);
  unsigned* ent16 = (unsigned*)alloc((size_t)N * 64 * 4);
  unsigned* fsrc0 = (unsigned*)alloc((size_t)N * 128 * 4);
  unsigned* fsrc1 = (unsigned*)alloc((size_t)N * 128 * 4);
  float4* expS4 = (float4*)alloc((size_t)R * 16);
  float4* inv4  = (float4*)alloc((size_t)N * 16);
  unsigned* pk = (unsigned*)alloc((size_t)T * 4);

  dim3 b256(256);
  rowptr3_kernel<<<(3 * (N + 1) + 255) / 256, b256, 0, stream>>>(
      adj, ent_m, rel_m, T, N, ptr_adj, ptr_ent, ptr_rel);
  relprep_kernel<<<(R + 3) / 4, b256, 0, stream>>>(rel_emb, e_attn, r_attn, R,
                                                   expS4, rnorm, rel16);
  pack_f16_kernel<<<(N * 64 + 255) / 256, b256, 0, stream>>>(ent_emb, ent16,
                                                             N * 64);
  pack_edges_kernel<<<(T + 255) / 256, b256, 0, stream>>>(adj, idx, pk, T);
  pack_all_kernel<<<192, b256, 0, stream>>>(e_proxy, e_gate, r_proxy, r_gate,
                                            b1e, b2e, b3e, b1r, b2r, b3r);

  int grow = (N + 3) / 4;
  stats4_kernel<<<grow, b256, 0, stream>>>(ptr_adj, pk, expS4, inv4, N);
  agg_fused_kernel<<<grow, b256, 0, stream>>>(ptr_ent, ent_m, ent16, ptr_rel,
                                              rel_m, rel16, fsrc0, N);
  // layer0: fsrc0 -> fsrc1 ; layer1: -> scratch planes at row ends of d_out
  unsigned* outu = (unsigned*)out;
  layer_rec_kernel<<<grow, b256, 0, stream>>>(ptr_adj, pk, expS4, inv4, rnorm,
                                              fsrc0, fsrc1, fsrc1 + 64, 128,
                                              N, 0);
  layer_rec_kernel<<<grow, b256, 0, stream>>>(ptr_adj, pk, expS4, inv4, rnorm,
                                              fsrc1, outu, outu + 704, 768,
                                              N, 1);

  // fused finals: both sides in one dispatch (race-free by plane layout)
  int fblocks = 2 * ((N + 31) / 32);
  final_fused_kernel<<<fblocks, b256, 0, stream>>>(
      fsrc0, fsrc1, outu, b1e, b2e, b3e, b1r, b2r, b3r, e_bias, r_bias, out);
}

// Round 10
// 305.699 us; speedup vs baseline: 1.0213x; 1.0213x over previous
//
#include <hip/hip_runtime.h>
#include <hip/hip_fp16.h>

// ---------------------------------------------------------------------------
// OverAll graph-attention pipeline, MI355X (gfx950)
// N=40000 rows, R=2000 relations, T=500000 edges, D=128, DEPTH=2, DC=384
//
// Round-8 proven structure + (a) shift-free softmax prep (scores bounded by
// sqrt(128) => exp f32-safe; stats4 one pass, weight kernel exp-free),
// (b) finals: software-prefetched B fragments (depth-1) in GEMM1/GEMM3 and
// __launch_bounds__(256,4) for a 128-VGPR budget (LDS caps 16 waves/CU).
//
// Dataflow (fp16 planar staging, E-plane uints [0,64), R-plane [64,128)):
//   agg -> fsrc0 ; layer0 -> fsrc1 ;
//   layer1 -> scratch planes in d_out rows: E at uints [0,64), R at [704,768)
//   final_fused (ONE dispatch, both sides by blockIdx parity) -> d_out f32.
// ---------------------------------------------------------------------------

typedef __attribute__((ext_vector_type(4))) float f32x4;
typedef _Float16 h16x2 __attribute__((ext_vector_type(2)));
typedef _Float16 f16x8 __attribute__((ext_vector_type(8)));
typedef float f32x16 __attribute__((ext_vector_type(16)));

__device__ __forceinline__ float wave_sum(float v) {
#pragma unroll
  for (int o = 32; o > 0; o >>= 1) v += __shfl_xor(v, o, 64);
  return v;
}
__device__ __forceinline__ float wave_max(float v) {
#pragma unroll
  for (int o = 32; o > 0; o >>= 1) v = fmaxf(v, __shfl_xor(v, o, 64));
  return v;
}
__device__ __forceinline__ unsigned pkhalf2(float a, float b) {
  __half2 h = __floats2half2_rn(a, b);
  return __builtin_bit_cast(unsigned, h);
}
__device__ __forceinline__ float bcf(unsigned u) {
  return __builtin_bit_cast(float, u);
}
__device__ __forceinline__ unsigned short f2h(float x) {
  return __builtin_bit_cast(unsigned short, (_Float16)x);
}
__device__ __forceinline__ float h2f(unsigned short h) {
  return (float)__builtin_bit_cast(_Float16, h);
}
__device__ __forceinline__ float tanh_fast(float x) {
  float t = __expf(-2.f * fabsf(x));
  float y = (1.f - t) / (1.f + t);
  return copysignf(y, x);
}
__device__ __forceinline__ float fdot2u(unsigned a, unsigned b, float c) {
#if __has_builtin(__builtin_amdgcn_fdot2)
  return __builtin_amdgcn_fdot2(__builtin_bit_cast(h16x2, a),
                                __builtin_bit_cast(h16x2, b), c, false);
#else
  h16x2 x = __builtin_bit_cast(h16x2, a), y = __builtin_bit_cast(h16x2, b);
  return fmaf((float)x.x, (float)y.x, fmaf((float)x.y, (float)y.y, c));
#endif
}
__device__ __forceinline__ float dot8(uint4 a, uint4 b) {
  return fdot2u(a.w, b.w, fdot2u(a.z, b.z, fdot2u(a.y, b.y,
         fdot2u(a.x, b.x, 0.f))));
}

// ---------------------------------------------------------------------------
__global__ void rowptr3_kernel(const int* __restrict__ e0,
                               const int* __restrict__ e1,
                               const int* __restrict__ e2, int T, int N,
                               int* __restrict__ p0, int* __restrict__ p1,
                               int* __restrict__ p2) {
  int tid = blockIdx.x * blockDim.x + threadIdx.x;
  int which = tid / (N + 1);
  int r = tid - which * (N + 1);
  if (which >= 3) return;
  const int* E = which == 0 ? e0 : (which == 1 ? e1 : e2);
  int* P = which == 0 ? p0 : (which == 1 ? p1 : p2);
  int lo = 0, hi = T;
  while (lo < hi) {
    int mid = (lo + hi) >> 1;
    if (E[2 * mid] < r) lo = mid + 1; else hi = mid;
  }
  P[r] = lo;
}

// Per relation: fp16 normalized vec + fp16 raw vec + exp(score) float4 table.
// Scores bounded: |l2(rel).attn| <= sqrt(128) ~ 11.4 -> exp in [1e-5, 9e4].
__global__ void relprep_kernel(const float* __restrict__ rel_emb,
                               const float* __restrict__ e_attn,
                               const float* __restrict__ r_attn, int R,
                               float4* __restrict__ expS4,
                               unsigned* __restrict__ rnorm,
                               unsigned* __restrict__ rel16) {
  int r = blockIdx.x * 4 + (threadIdx.x >> 6);
  int lane = threadIdx.x & 63;
  if (r >= R) return;
  float2 v  = *(const float2*)(rel_emb + (size_t)r * 128 + 2 * lane);
  float2 a0 = *(const float2*)(e_attn + 2 * lane);
  float2 a1 = *(const float2*)(e_attn + 128 + 2 * lane);
  float2 b0 = *(const float2*)(r_attn + 2 * lane);
  float2 b1 = *(const float2*)(r_attn + 128 + 2 * lane);
  float n  = wave_sum(v.x * v.x + v.y * v.y);
  float d0 = wave_sum(v.x * a0.x + v.y * a0.y);
  float d1 = wave_sum(v.x * a1.x + v.y * a1.y);
  float d2 = wave_sum(v.x * b0.x + v.y * b0.y);
  float d3 = wave_sum(v.x * b1.x + v.y * b1.y);
  float inv = 1.f / fmaxf(sqrtf(n), 1e-12f);
  rnorm[(size_t)r * 64 + lane] = pkhalf2(v.x * inv, v.y * inv);
  rel16[(size_t)r * 64 + lane] = pkhalf2(v.x, v.y);
  if (lane == 0) {
    // x = E/layer0, y = E/layer1, z = R/layer0, w = R/layer1
    expS4[r] = make_float4(__expf(d0 * inv), __expf(d1 * inv),
                           __expf(d2 * inv), __expf(d3 * inv));
  }
}

__global__ void pack_f16_kernel(const float* __restrict__ src,
                                unsigned* __restrict__ dst, int n2) {
  int i = blockIdx.x * blockDim.x + threadIdx.x;
  if (i >= n2) return;
  float2 v = *(const float2*)(src + 2 * (size_t)i);
  dst[i] = pkhalf2(v.x, v.y);
}

// pk[e] = col | rel<<16
__global__ void pack_edges_kernel(const int* __restrict__ adj,
                                  const int* __restrict__ idx,
                                  unsigned* __restrict__ pk, int T) {
  int e = blockIdx.x * blockDim.x + threadIdx.x;
  if (e >= T) return;
  pk[e] = (unsigned)adj[2 * e + 1] | ((unsigned)idx[2 * e + 1] << 16);
}

// Shift-free softmax denominators for all 4 tables (single pass, no exp).
__global__ __launch_bounds__(256) void stats4_kernel(
    const int* __restrict__ ptr, const unsigned* __restrict__ pk,
    const float4* __restrict__ expS4, float4* __restrict__ inv4, int N) {
  int r = blockIdx.x * 4 + (threadIdx.x >> 6);
  if (r >= N) return;
  int lane = threadIdx.x & 63;
  int beg = ptr[r], end = ptr[r + 1];
  float d0 = 0.f, d1 = 0.f, d2 = 0.f, d3 = 0.f;
  for (int e = beg + lane; e < end; e += 64) {
    float4 es = expS4[pk[e] >> 16];
    d0 += es.x; d1 += es.y; d2 += es.z; d3 += es.w;
  }
#pragma unroll
  for (int o = 32; o > 0; o >>= 1) {
    d0 += __shfl_xor(d0, o, 64); d1 += __shfl_xor(d1, o, 64);
    d2 += __shfl_xor(d2, o, 64); d3 += __shfl_xor(d3, o, 64);
  }
  if (lane == 0) {
    inv4[r] = make_float4(d0 > 0.f ? 1.f / d0 : 0.f,
                          d1 > 0.f ? 1.f / d1 : 0.f,
                          d2 > 0.f ? 1.f / d2 : 0.f,
                          d3 > 0.f ? 1.f / d3 : 0.f);
  }
}

// Edge-parallel weights (exp-free): wt_l[e] = (wE, wR) f32, sequential write.
__global__ void weight_kernel(const int* __restrict__ adj,
                              const unsigned* __restrict__ pk,
                              const float4* __restrict__ expS4,
                              const float4* __restrict__ inv4,
                              uint2* __restrict__ wt0,
                              uint2* __restrict__ wt1, int T) {
  int e = blockIdx.x * blockDim.x + threadIdx.x;
  if (e >= T) return;
  int row = adj[2 * e];
  int rel = (int)(pk[e] >> 16);
  float4 es = expS4[rel];
  float4 iv = inv4[row];
  wt0[e] = make_uint2(__builtin_bit_cast(unsigned, es.x * iv.x),
                      __builtin_bit_cast(unsigned, es.z * iv.z));
  wt1[e] = make_uint2(__builtin_bit_cast(unsigned, es.y * iv.y),
                      __builtin_bit_cast(unsigned, es.w * iv.w));
}

// ---------------------------------------------------------------------------
__global__ __launch_bounds__(256) void agg_fused_kernel(
    const int* __restrict__ ptrE, const int* __restrict__ edgesE,
    const unsigned* __restrict__ ent16, const int* __restrict__ ptrR,
    const int* __restrict__ edgesR, const unsigned* __restrict__ rel16,
    unsigned* __restrict__ fout, int N) {
  int r = blockIdx.x * 4 + (threadIdx.x >> 6);
  if (r >= N) return;
  int lane = threadIdx.x & 63;
  int g = lane >> 4, q = lane & 15;

  float aE[8] = {0, 0, 0, 0, 0, 0, 0, 0};
  float aR[8] = {0, 0, 0, 0, 0, 0, 0, 0};

  auto addh = [&](uint4 u, float* a) {
    h16x2 h0 = __builtin_bit_cast(h16x2, u.x), h1 = __builtin_bit_cast(h16x2, u.y);
    h16x2 h2 = __builtin_bit_cast(h16x2, u.z), h3 = __builtin_bit_cast(h16x2, u.w);
    a[0] += (float)h0.x; a[1] += (float)h0.y;
    a[2] += (float)h1.x; a[3] += (float)h1.y;
    a[4] += (float)h2.x; a[5] += (float)h2.y;
    a[6] += (float)h3.x; a[7] += (float)h3.y;
  };

  int begE = ptrE[r], endE = ptrE[r + 1];
  for (int e0 = begE; e0 < endE; e0 += 8) {
    int eA = e0 + g, eB = e0 + 4 + g;
    if (eA < endE)
      addh(*(const uint4*)(ent16 + (size_t)edgesE[2 * eA + 1] * 64 + 4 * q), aE);
    if (eB < endE)
      addh(*(const uint4*)(ent16 + (size_t)edgesE[2 * eB + 1] * 64 + 4 * q), aE);
  }
  int begR = ptrR[r], endR = ptrR[r + 1];
  for (int e0 = begR; e0 < endR; e0 += 8) {
    int eA = e0 + g, eB = e0 + 4 + g;
    if (eA < endR)
      addh(*(const uint4*)(rel16 + (size_t)edgesR[2 * eA + 1] * 64 + 4 * q), aR);
    if (eB < endR)
      addh(*(const uint4*)(rel16 + (size_t)edgesR[2 * eB + 1] * 64 + 4 * q), aR);
  }
#pragma unroll
  for (int j = 0; j < 8; ++j) {
    aE[j] += __shfl_xor(aE[j], 16, 64); aE[j] += __shfl_xor(aE[j], 32, 64);
    aR[j] += __shfl_xor(aR[j], 16, 64); aR[j] += __shfl_xor(aR[j], 32, 64);
  }
  float sE = (endE > begE) ? 1.f / (float)(endE - begE) : 0.f;
  float sR = (endR > begR) ? 1.f / (float)(endR - begR) : 0.f;
  if (g == 0) {
    float t[8];
#pragma unroll
    for (int j = 0; j < 8; ++j) t[j] = tanh_fast(aE[j] * sE);
    uint4 u;
    u.x = pkhalf2(t[0], t[1]); u.y = pkhalf2(t[2], t[3]);
    u.z = pkhalf2(t[4], t[5]); u.w = pkhalf2(t[6], t[7]);
    *(uint4*)(fout + (size_t)r * 128 + 4 * q) = u;
  } else if (g == 1) {
    float t[8];
#pragma unroll
    for (int j = 0; j < 8; ++j) t[j] = tanh_fast(aR[j] * sR);
    uint4 u;
    u.x = pkhalf2(t[0], t[1]); u.y = pkhalf2(t[2], t[3]);
    u.z = pkhalf2(t[4], t[5]); u.w = pkhalf2(t[6], t[7]);
    *(uint4*)(fout + (size_t)r * 128 + 64 + 4 * q) = u;
  }
}

// ---------------------------------------------------------------------------
// Record-driven fused e+r layer (Round-8 proven form: batch-2, materialized
// sequential weights).
__global__ __launch_bounds__(256) void layer_rec_kernel(
    const int* __restrict__ ptr, const unsigned* __restrict__ pk,
    const uint2* __restrict__ wt, const unsigned* __restrict__ rnorm,
    const unsigned* __restrict__ fin, unsigned* __restrict__ foutE,
    unsigned* __restrict__ foutR, int fstride, int N) {
  int r = blockIdx.x * 4 + (threadIdx.x >> 6);
  if (r >= N) return;
  int lane = threadIdx.x & 63;
  int g = lane >> 4, q = lane & 15;
  int beg = ptr[r], end = ptr[r + 1];

  float aE[8] = {0, 0, 0, 0, 0, 0, 0, 0};
  float aR[8] = {0, 0, 0, 0, 0, 0, 0, 0};

  auto accum = [&](uint4 F, uint4 V, float w, float s, float* a) {
    h16x2 f0 = __builtin_bit_cast(h16x2, F.x), v0 = __builtin_bit_cast(h16x2, V.x);
    h16x2 f1 = __builtin_bit_cast(h16x2, F.y), v1 = __builtin_bit_cast(h16x2, V.y);
    h16x2 f2 = __builtin_bit_cast(h16x2, F.z), v2 = __builtin_bit_cast(h16x2, V.z);
    h16x2 f3 = __builtin_bit_cast(h16x2, F.w), v3 = __builtin_bit_cast(h16x2, V.w);
    a[0] = fmaf((float)f0.x, w, fmaf((float)v0.x, s, a[0]));
    a[1] = fmaf((float)f0.y, w, fmaf((float)v0.y, s, a[1]));
    a[2] = fmaf((float)f1.x, w, fmaf((float)v1.x, s, a[2]));
    a[3] = fmaf((float)f1.y, w, fmaf((float)v1.y, s, a[3]));
    a[4] = fmaf((float)f2.x, w, fmaf((float)v2.x, s, a[4]));
    a[5] = fmaf((float)f2.y, w, fmaf((float)v2.y, s, a[5]));
    a[6] = fmaf((float)f3.x, w, fmaf((float)v3.x, s, a[6]));
    a[7] = fmaf((float)f3.y, w, fmaf((float)v3.y, s, a[7]));
  };

  for (int e0 = beg; e0 < end; e0 += 8) {
    int eA = e0 + g, eB = e0 + 4 + g;
    bool actA = eA < end, actB = eB < end;
    unsigned pkA = actA ? pk[eA] : 0u;
    unsigned pkB = actB ? pk[eB] : 0u;
    uint2 wA = actA ? wt[eA] : make_uint2(0u, 0u);
    uint2 wB = actB ? wt[eB] : make_uint2(0u, 0u);
    int colA = (int)(pkA & 0xFFFFu), relA = (int)(pkA >> 16);
    int colB = (int)(pkB & 0xFFFFu), relB = (int)(pkB >> 16);
    float wAE = bcf(wA.x), wAR = bcf(wA.y);
    float wBE = bcf(wB.x), wBR = bcf(wB.y);

    const unsigned* fA = fin + (size_t)colA * 128;
    const unsigned* fB = fin + (size_t)colB * 128;
    uint4 EA = *(const uint4*)(fA + 4 * q);
    uint4 RA = *(const uint4*)(fA + 64 + 4 * q);
    uint4 VA = *(const uint4*)(rnorm + (size_t)relA * 64 + 4 * q);
    uint4 EB = *(const uint4*)(fB + 4 * q);
    uint4 RB = *(const uint4*)(fB + 64 + 4 * q);
    uint4 VB = *(const uint4*)(rnorm + (size_t)relB * 64 + 4 * q);

    float dAE = dot8(EA, VA), dAR = dot8(RA, VA);
    float dBE = dot8(EB, VB), dBR = dot8(RB, VB);
#pragma unroll
    for (int m = 1; m < 16; m <<= 1) {
      dAE += __shfl_xor(dAE, m, 64);
      dAR += __shfl_xor(dAR, m, 64);
      dBE += __shfl_xor(dBE, m, 64);
      dBR += __shfl_xor(dBR, m, 64);
    }
    float sAE = -2.f * wAE * dAE, sAR = -2.f * wAR * dAR;
    float sBE = -2.f * wBE * dBE, sBR = -2.f * wBR * dBR;
    accum(EA, VA, wAE, sAE, aE);
    accum(RA, VA, wAR, sAR, aR);
    accum(EB, VB, wBE, sBE, aE);
    accum(RB, VB, wBR, sBR, aR);
  }

#pragma unroll
  for (int j = 0; j < 8; ++j) {
    aE[j] += __shfl_xor(aE[j], 16, 64); aE[j] += __shfl_xor(aE[j], 32, 64);
    aR[j] += __shfl_xor(aR[j], 16, 64); aR[j] += __shfl_xor(aR[j], 32, 64);
  }
  if (g == 0) {
    float t[8];
#pragma unroll
    for (int j = 0; j < 8; ++j) t[j] = tanh_fast(aE[j]);
    uint4 u;
    u.x = pkhalf2(t[0], t[1]); u.y = pkhalf2(t[2], t[3]);
    u.z = pkhalf2(t[4], t[5]); u.w = pkhalf2(t[6], t[7]);
    *(uint4*)(foutE + (size_t)r * fstride + 4 * q) = u;
  } else if (g == 1) {
    float t[8];
#pragma unroll
    for (int j = 0; j < 8; ++j) t[j] = tanh_fast(aR[j]);
    uint4 u;
    u.x = pkhalf2(t[0], t[1]); u.y = pkhalf2(t[2], t[3]);
    u.z = pkhalf2(t[4], t[5]); u.w = pkhalf2(t[6], t[7]);
    *(uint4*)(foutR + (size_t)r * fstride + 4 * q) = u;
  }
}

// ---------------------------------------------------------------------------
// Pack B matrices into f16 MFMA 32x32x16 fragment order.
__device__ __forceinline__ void pack_one32(const float* __restrict__ src,
                                           unsigned short* __restrict__ dst,
                                           int NT, int srcld, int mode, int f,
                                           int lane) {
  int kt = f / NT, nt = f % NT;
  int kbase = 16 * kt + 8 * (lane >> 5);
  int n = 32 * nt + (lane & 31);
  unsigned short tmp[8];
#pragma unroll
  for (int j = 0; j < 8; ++j) {
    int k = kbase + j;
    float v = (mode == 0) ? src[(size_t)k * srcld + n] : src[(size_t)n * srcld + k];
    tmp[j] = f2h(v);
  }
  *(uint4*)(dst + ((size_t)f * 64 + lane) * 8) = *(uint4*)tmp;
}
__global__ void pack_all_kernel(const float* eP, const float* eG,
                                const float* rP, const float* rG,
                                unsigned short* b1e, unsigned short* b2e,
                                unsigned short* b3e, unsigned short* b1r,
                                unsigned short* b2r, unsigned short* b3r) {
  int f = blockIdx.x * 4 + (threadIdx.x >> 6);
  int lane = threadIdx.x & 63;
  if (f < 48)       pack_one32(eP, b1e, 2, 384, 1, f, lane);
  else if (f < 96)  pack_one32(eP, b2e, 12, 384, 0, f - 48, lane);
  else if (f < 384) pack_one32(eG, b3e, 12, 384, 0, f - 96, lane);
  else if (f < 432) pack_one32(rP, b1r, 2, 384, 1, f - 384, lane);
  else if (f < 480) pack_one32(rP, b2r, 12, 384, 0, f - 432, lane);
  else if (f < 768) pack_one32(rG, b3r, 12, 384, 0, f - 480, lane);
}

// ---------------------------------------------------------------------------
// Fused proxy/gate epilogue: both sides in one dispatch (side = blockIdx&1).
// 32 rows/block, 256 threads (4 waves), f16 MFMA 32x32x16, B prefetch depth-1.
// C/D layout: col = lane&31, row = (reg&3) + 8*(reg>>2) + 4*(lane>>5).
__global__ __launch_bounds__(256, 4) void final_fused_kernel(
    const unsigned* __restrict__ f0, const unsigned* __restrict__ f1,
    const unsigned* __restrict__ outu,
    const unsigned short* __restrict__ B1e, const unsigned short* __restrict__ B2e,
    const unsigned short* __restrict__ B3e, const unsigned short* __restrict__ B1r,
    const unsigned short* __restrict__ B2r, const unsigned short* __restrict__ B3r,
    const float* __restrict__ biasE, const float* __restrict__ biasR,
    float* __restrict__ gout) {
  __shared__ __align__(16) unsigned sOutH[32][204];   // fp16 pairs (192 used)
  __shared__ __align__(16) float sPa[32][68];
  __shared__ __align__(16) unsigned short sPaH[32][72];
  __shared__ float sInv[32];
  unsigned short* sOutHs = (unsigned short*)&sOutH[0][0];  // row stride 408

  const int side = blockIdx.x & 1;
  const int row0 = (blockIdx.x >> 1) * 32;
  const int plane = side ? 64 : 0;
  const unsigned* f2 = outu + (side ? 704 : 0);
  const unsigned short* B1 = side ? B1r : B1e;
  const unsigned short* B2 = side ? B2r : B2e;
  const unsigned short* B3 = side ? B3r : B3e;
  const float* bias = side ? biasR : biasE;
  const int coloff = side ? 384 : 0;

  const int t = threadIdx.x;
  const int w = t >> 6, lane = t & 63;
  const int l31 = lane & 31, l5 = lane >> 5;

  // 1. load outputs planes + fused row sumsq (8 threads per row)
  {
    int rloc = t >> 3;      // 0..31
    int c0 = t & 7;
    int rg = row0 + rloc;
    float ss = 0.f;
#pragma unroll
    for (int i = 0; i < 6; ++i) {
      int c = c0 + 8 * i;   // 0..47
      int buf = c >> 4, j = c & 15;
      const unsigned* src;
      if (buf == 0)      src = f0 + (size_t)rg * 128 + plane + 4 * j;
      else if (buf == 1) src = f1 + (size_t)rg * 128 + plane + 4 * j;
      else               src = f2 + (size_t)rg * 768 + 4 * j;
      uint4 u = *(const uint4*)src;
      *(uint4*)&sOutH[rloc][c * 4] = u;
      ss = fdot2u(u.x, u.x, fdot2u(u.y, u.y,
           fdot2u(u.z, u.z, fdot2u(u.w, u.w, ss))));
    }
    ss += __shfl_xor(ss, 1, 64);
    ss += __shfl_xor(ss, 2, 64);
    ss += __shfl_xor(ss, 4, 64);
    if (c0 == 0) sInv[rloc] = 1.f / fmaxf(sqrtf(ss), 1e-12f);
  }
  __syncthreads();

  // 2. GEMM1: S = outputs @ proxyT (waves 0,1; ct = w), B prefetch depth-1
  if (w < 2) {
    int ct = w;
    f32x16 acc = {0.f, 0.f, 0.f, 0.f, 0.f, 0.f, 0.f, 0.f,
                  0.f, 0.f, 0.f, 0.f, 0.f, 0.f, 0.f, 0.f};
    f16x8 bh = *(const f16x8*)(B1 + ((size_t)ct * 64 + lane) * 8);
#pragma unroll
    for (int kt = 0; kt < 24; ++kt) {
      f16x8 bn;
      if (kt < 23)
        bn = *(const f16x8*)(B1 + ((size_t)((kt + 1) * 2 + ct) * 64 + lane) * 8);
      f16x8 a = __builtin_bit_cast(
          f16x8, *(const uint4*)&sOutH[l31][8 * kt + 4 * l5]);
      acc = __builtin_amdgcn_mfma_f32_32x32x16_f16(a, bh, acc, 0, 0, 0);
      bh = bn;
    }
#pragma unroll
    for (int reg = 0; reg < 16; ++reg) {
      int row = (reg & 3) + 8 * (reg >> 2) + 4 * l5;
      sPa[row][ct * 32 + l31] = acc[reg] * sInv[row];
    }
  }
  __syncthreads();

  // 3. softmax over 64 proxies (8 rows/wave) -> f16 pa
  for (int rr = 8 * w; rr < 8 * w + 8; ++rr) {
    float v = sPa[rr][lane];
    float mx = wave_max(v);
    float e = __expf(v - mx);
    float s = wave_sum(e);
    sPaH[rr][lane] = f2h(e / s);
  }
  __syncthreads();

  // 4. GEMM2: pf = outputs - pa @ proxy; overwrite sOutH with pf,
  //    stash outputs bits in regs. wave w -> strips 3w..3w+2
  const int ntb = 3 * w;
  unsigned outv[3][8];
  {
    f32x16 acc2[3];
#pragma unroll
    for (int s = 0; s < 3; ++s)
#pragma unroll
      for (int i = 0; i < 16; ++i) acc2[s][i] = 0.f;
#pragma unroll
    for (int kt = 0; kt < 4; ++kt) {
      f16x8 a = __builtin_bit_cast(
          f16x8, *(const uint4*)&sPaH[l31][16 * kt + 8 * l5]);
#pragma unroll
      for (int s = 0; s < 3; ++s) {
        f16x8 b = *(const f16x8*)(B2 + ((size_t)(kt * 12 + ntb + s) * 64 + lane) * 8);
        acc2[s] = __builtin_amdgcn_mfma_f32_32x32x16_f16(a, b, acc2[s], 0, 0, 0);
      }
    }
#pragma unroll
    for (int s = 0; s < 3; ++s) {
      int col = 32 * (ntb + s) + l31;
#pragma unroll
      for (int p = 0; p < 8; ++p) {
        int ra = ((2 * p) & 3) + 8 * (p >> 1) + 4 * l5;
        unsigned short u0 = sOutHs[ra * 408 + col];
        unsigned short u1 = sOutHs[(ra + 1) * 408 + col];
        outv[s][p] = (unsigned)u0 | ((unsigned)u1 << 16);
        float pf0 = h2f(u0) - acc2[s][2 * p];
        float pf1 = h2f(u1) - acc2[s][2 * p + 1];
        sOutHs[ra * 408 + col] = f2h(pf0);
        sOutHs[(ra + 1) * 408 + col] = f2h(pf1);
      }
    }
  }
  __syncthreads();

  // 5. GEMM3: gate logits = pf @ gateK (kt-outer, A reused across 3 strips,
  //    B prefetch depth-1)
  f32x16 acc3[3];
#pragma unroll
  for (int s = 0; s < 3; ++s)
#pragma unroll
    for (int i = 0; i < 16; ++i) acc3[s][i] = 0.f;
  {
    f16x8 bh0 = *(const f16x8*)(B3 + ((size_t)(ntb + 0) * 64 + lane) * 8);
    f16x8 bh1 = *(const f16x8*)(B3 + ((size_t)(ntb + 1) * 64 + lane) * 8);
    f16x8 bh2 = *(const f16x8*)(B3 + ((size_t)(ntb + 2) * 64 + lane) * 8);
#pragma unroll
    for (int kt = 0; kt < 24; ++kt) {
      f16x8 bn0, bn1, bn2;
      if (kt < 23) {
        bn0 = *(const f16x8*)(B3 + ((size_t)((kt + 1) * 12 + ntb + 0) * 64 + lane) * 8);
        bn1 = *(const f16x8*)(B3 + ((size_t)((kt + 1) * 12 + ntb + 1) * 64 + lane) * 8);
        bn2 = *(const f16x8*)(B3 + ((size_t)((kt + 1) * 12 + ntb + 2) * 64 + lane) * 8);
      }
      f16x8 a = __builtin_bit_cast(
          f16x8, *(const uint4*)&sOutH[l31][8 * kt + 4 * l5]);
      acc3[0] = __builtin_amdgcn_mfma_f32_32x32x16_f16(a, bh0, acc3[0], 0, 0, 0);
      acc3[1] = __builtin_amdgcn_mfma_f32_32x32x16_f16(a, bh1, acc3[1], 0, 0, 0);
      acc3[2] = __builtin_amdgcn_mfma_f32_32x32x16_f16(a, bh2, acc3[2], 0, 0, 0);
      bh0 = bn0; bh1 = bn1; bh2 = bn2;
    }
  }

  // 6. sigmoid gate + combine + store
#pragma unroll
  for (int s = 0; s < 3; ++s) {
    int col = 32 * (ntb + s) + l31;
    float bv = bias[col];
#pragma unroll
    for (int p = 0; p < 8; ++p) {
      int ra = ((2 * p) & 3) + 8 * (p >> 1) + 4 * l5;
      float g0 = 1.f / (1.f + __expf(-(acc3[s][2 * p] + bv)));
      float g1 = 1.f / (1.f + __expf(-(acc3[s][2 * p + 1] + bv)));
      float pf0 = h2f(sOutHs[ra * 408 + col]);
      float pf1 = h2f(sOutHs[(ra + 1) * 408 + col]);
      unsigned ov = outv[s][p];
      float o0 = h2f((unsigned short)(ov & 0xffffu));
      float o1 = h2f((unsigned short)(ov >> 16));
      gout[(size_t)(row0 + ra) * 768 + coloff + col] = g0 * o0 + (1.f - g0) * pf0;
      gout[(size_t)(row0 + ra + 1) * 768 + coloff + col] =
          g1 * o1 + (1.f - g1) * pf1;
    }
  }
}

extern "C" void kernel_launch(void* const* d_in, const int* in_sizes, int n_in,
                              void* d_out, int out_size, void* d_ws,
                              size_t ws_size, hipStream_t stream) {
  (void)n_in; (void)out_size; (void)ws_size;
  const float* ent_emb = (const float*)d_in[0];
  const float* rel_emb = (const float*)d_in[1];
  const float* e_gate  = (const float*)d_in[2];
  const float* e_proxy = (const float*)d_in[3];
  const float* e_bias  = (const float*)d_in[4];
  const float* e_attn  = (const float*)d_in[5];
  const float* r_gate  = (const float*)d_in[6];
  const float* r_proxy = (const float*)d_in[7];
  const float* r_bias  = (const float*)d_in[8];
  const float* r_attn  = (const float*)d_in[9];
  const int* adj   = (const int*)d_in[11];
  const int* idx   = (const int*)d_in[12];
  const int* ent_m = (const int*)d_in[13];
  const int* rel_m = (const int*)d_in[14];
  const int N = in_sizes[0] / 128;
  const int R = in_sizes[1] / 128;
  const int T = in_sizes[10];
  float* out = (float*)d_out;

  char* w = (char*)d_ws;
  size_t used = 0;
  auto alloc = [&](size_t bytes) {
    void* p = (void*)(w + used);
    used += (bytes + 255) & ~(size_t)255;
    return p;
  };
  int* ptr_adj  = (int*)alloc((size_t)(N + 1) * sizeof(int));
  int* ptr_ent  = (int*)alloc((size_t)(N + 1) * sizeof(int));
  int* ptr_rel  = (int*)alloc((size_t)(N + 1) * sizeof(int));
  unsigned short* b1e = (unsigned short*)alloc(48 * 1024);
  unsigned short* b2e = (unsigned short*)alloc(48 * 1024);
  unsigned short* b3e = (unsigned short*)alloc(288 * 1024);
  unsigned short* b1r = (unsigned short*)alloc(48 * 1024);
  unsigned short* b2r = (unsigned short*)alloc(48 * 1024);
  unsigned short* b3r = (unsigned short*)alloc(288 * 1024);
  unsigned* rnorm = (unsigned*)alloc((size_t)R * 64 * 4);
  unsigned* rel16 = (unsigned*)alloc((size_t)R * 64 * 4);
  unsigned* ent16 = (unsigned*)alloc((size_t)N * 64 * 4);
  unsigned* fsrc0 = (unsigned*)alloc((size_t)N * 128 * 4);
  unsigned* fsrc1 = (unsigned*)alloc((size_t)N * 128 * 4);
  float4* expS4 = (float4*)alloc((size_t)R * 16);
  float4* inv4  = (float4*)alloc((size_t)N * 16);
  unsigned* pk = (unsigned*)alloc((size_t)T * 4);
  uint2* wt0 = (uint2*)alloc((size_t)T * 8);
  uint2* wt1 = (uint2*)alloc((size_t)T * 8);

  dim3 b256(256);
  rowptr3_kernel<<<(3 * (N + 1) + 255) / 256, b256, 0, stream>>>(
      adj, ent_m, rel_m, T, N, ptr_adj, ptr_ent, ptr_rel);
  relprep_kernel<<<(R + 3) / 4, b256, 0, stream>>>(rel_emb, e_attn, r_attn, R,
                                                   expS4, rnorm, rel16);
  pack_f16_kernel<<<(N * 64 + 255) / 256, b256, 0, stream>>>(ent_emb, ent16,
                                                             N * 64);
  pack_edges_kernel<<<(T + 255) / 256, b256, 0, stream>>>(adj, idx, pk, T);
  pack_all_kernel<<<192, b256, 0, stream>>>(e_proxy, e_gate, r_proxy, r_gate,
                                            b1e, b2e, b3e, b1r, b2r, b3r);

  int grow = (N + 3) / 4;
  stats4_kernel<<<grow, b256, 0, stream>>>(ptr_adj, pk, expS4, inv4, N);
  weight_kernel<<<(T + 255) / 256, b256, 0, stream>>>(adj, pk, expS4, inv4,
                                                      wt0, wt1, T);
  agg_fused_kernel<<<grow, b256, 0, stream>>>(ptr_ent, ent_m, ent16, ptr_rel,
                                              rel_m, rel16, fsrc0, N);
  // layer0: fsrc0 -> fsrc1 ; layer1: -> scratch planes at row ends of d_out
  unsigned* outu = (unsigned*)out;
  layer_rec_kernel<<<grow, b256, 0, stream>>>(ptr_adj, pk, wt0, rnorm, fsrc0,
                                              fsrc1, fsrc1 + 64, 128, N);
  layer_rec_kernel<<<grow, b256, 0, stream>>>(ptr_adj, pk, wt1, rnorm, fsrc1,
                                              outu, outu + 704, 768, N);

  // fused finals: both sides in one dispatch (race-free by plane layout)
  int fblocks = 2 * ((N + 31) / 32);
  final_fused_kernel<<<fblocks, b256, 0, stream>>>(
      fsrc0, fsrc1, outu, b1e, b2e, b3e, b1r, b2r, b3r, e_bias, r_bias, out);
}

// Round 11
// 282.746 us; speedup vs baseline: 1.1042x; 1.0812x over previous
//
#include <hip/hip_runtime.h>
#include <hip/hip_fp16.h>

// ---------------------------------------------------------------------------
// OverAll graph-attention pipeline, MI355X (gfx950)
// N=40000 rows, R=2000 relations, T=500000 edges, D=128, DEPTH=2, DC=384
//
// Structure: Round-8 proven kernels + Round-10 prep simplifications.
//  - shift-free softmax (scores bounded by sqrt(128) => exp f32-safe):
//    relprep emits expS4[rel]; stats4 one gather pass (no exp/max);
//    weight kernel exp-free (2 muls/edge).
//  - finals: EXACT Round-9 config (plain launch_bounds(256), no prefetch,
//    no min-waves bound -> no spills; VGPR ~84, LDS 39.9KB).
//
// Dataflow (fp16 planar staging, E-plane uints [0,64), R-plane [64,128)):
//   agg -> fsrc0 ; layer0 -> fsrc1 ;
//   layer1 -> scratch planes in d_out rows: E at uints [0,64), R at [704,768)
//   final_fused (ONE dispatch, both sides by blockIdx parity) -> d_out f32.
//   Race-freedom: e-writes bytes[0,1536) vs r-reads bytes[2816,3072) disjoint;
//   r-writes bytes[1536,3072) vs e-reads bytes[0,256) disjoint.
// ---------------------------------------------------------------------------

typedef __attribute__((ext_vector_type(4))) float f32x4;
typedef _Float16 h16x2 __attribute__((ext_vector_type(2)));
typedef _Float16 f16x8 __attribute__((ext_vector_type(8)));
typedef float f32x16 __attribute__((ext_vector_type(16)));

__device__ __forceinline__ float wave_sum(float v) {
#pragma unroll
  for (int o = 32; o > 0; o >>= 1) v += __shfl_xor(v, o, 64);
  return v;
}
__device__ __forceinline__ float wave_max(float v) {
#pragma unroll
  for (int o = 32; o > 0; o >>= 1) v = fmaxf(v, __shfl_xor(v, o, 64));
  return v;
}
__device__ __forceinline__ unsigned pkhalf2(float a, float b) {
  __half2 h = __floats2half2_rn(a, b);
  return __builtin_bit_cast(unsigned, h);
}
__device__ __forceinline__ float bcf(unsigned u) {
  return __builtin_bit_cast(float, u);
}
__device__ __forceinline__ unsigned short f2h(float x) {
  return __builtin_bit_cast(unsigned short, (_Float16)x);
}
__device__ __forceinline__ float h2f(unsigned short h) {
  return (float)__builtin_bit_cast(_Float16, h);
}
__device__ __forceinline__ float tanh_fast(float x) {
  float t = __expf(-2.f * fabsf(x));
  float y = (1.f - t) / (1.f + t);
  return copysignf(y, x);
}
__device__ __forceinline__ float fdot2u(unsigned a, unsigned b, float c) {
#if __has_builtin(__builtin_amdgcn_fdot2)
  return __builtin_amdgcn_fdot2(__builtin_bit_cast(h16x2, a),
                                __builtin_bit_cast(h16x2, b), c, false);
#else
  h16x2 x = __builtin_bit_cast(h16x2, a), y = __builtin_bit_cast(h16x2, b);
  return fmaf((float)x.x, (float)y.x, fmaf((float)x.y, (float)y.y, c));
#endif
}
__device__ __forceinline__ float dot8(uint4 a, uint4 b) {
  return fdot2u(a.w, b.w, fdot2u(a.z, b.z, fdot2u(a.y, b.y,
         fdot2u(a.x, b.x, 0.f))));
}

// ---------------------------------------------------------------------------
__global__ void rowptr3_kernel(const int* __restrict__ e0,
                               const int* __restrict__ e1,
                               const int* __restrict__ e2, int T, int N,
                               int* __restrict__ p0, int* __restrict__ p1,
                               int* __restrict__ p2) {
  int tid = blockIdx.x * blockDim.x + threadIdx.x;
  int which = tid / (N + 1);
  int r = tid - which * (N + 1);
  if (which >= 3) return;
  const int* E = which == 0 ? e0 : (which == 1 ? e1 : e2);
  int* P = which == 0 ? p0 : (which == 1 ? p1 : p2);
  int lo = 0, hi = T;
  while (lo < hi) {
    int mid = (lo + hi) >> 1;
    if (E[2 * mid] < r) lo = mid + 1; else hi = mid;
  }
  P[r] = lo;
}

// Per relation: fp16 normalized vec + fp16 raw vec + exp(score) float4 table.
// Scores bounded: |l2(rel).attn| <= sqrt(128) ~ 11.4 -> exp in [1e-5, 9e4].
__global__ void relprep_kernel(const float* __restrict__ rel_emb,
                               const float* __restrict__ e_attn,
                               const float* __restrict__ r_attn, int R,
                               float4* __restrict__ expS4,
                               unsigned* __restrict__ rnorm,
                               unsigned* __restrict__ rel16) {
  int r = blockIdx.x * 4 + (threadIdx.x >> 6);
  int lane = threadIdx.x & 63;
  if (r >= R) return;
  float2 v  = *(const float2*)(rel_emb + (size_t)r * 128 + 2 * lane);
  float2 a0 = *(const float2*)(e_attn + 2 * lane);
  float2 a1 = *(const float2*)(e_attn + 128 + 2 * lane);
  float2 b0 = *(const float2*)(r_attn + 2 * lane);
  float2 b1 = *(const float2*)(r_attn + 128 + 2 * lane);
  float n  = wave_sum(v.x * v.x + v.y * v.y);
  float d0 = wave_sum(v.x * a0.x + v.y * a0.y);
  float d1 = wave_sum(v.x * a1.x + v.y * a1.y);
  float d2 = wave_sum(v.x * b0.x + v.y * b0.y);
  float d3 = wave_sum(v.x * b1.x + v.y * b1.y);
  float inv = 1.f / fmaxf(sqrtf(n), 1e-12f);
  rnorm[(size_t)r * 64 + lane] = pkhalf2(v.x * inv, v.y * inv);
  rel16[(size_t)r * 64 + lane] = pkhalf2(v.x, v.y);
  if (lane == 0) {
    // x = E/layer0, y = E/layer1, z = R/layer0, w = R/layer1
    expS4[r] = make_float4(__expf(d0 * inv), __expf(d1 * inv),
                           __expf(d2 * inv), __expf(d3 * inv));
  }
}

__global__ void pack_f16_kernel(const float* __restrict__ src,
                                unsigned* __restrict__ dst, int n2) {
  int i = blockIdx.x * blockDim.x + threadIdx.x;
  if (i >= n2) return;
  float2 v = *(const float2*)(src + 2 * (size_t)i);
  dst[i] = pkhalf2(v.x, v.y);
}

// pk[e] = col | rel<<16
__global__ void pack_edges_kernel(const int* __restrict__ adj,
                                  const int* __restrict__ idx,
                                  unsigned* __restrict__ pk, int T) {
  int e = blockIdx.x * blockDim.x + threadIdx.x;
  if (e >= T) return;
  pk[e] = (unsigned)adj[2 * e + 1] | ((unsigned)idx[2 * e + 1] << 16);
}

// Shift-free softmax denominators for all 4 tables (single pass, no exp).
__global__ __launch_bounds__(256) void stats4_kernel(
    const int* __restrict__ ptr, const unsigned* __restrict__ pk,
    const float4* __restrict__ expS4, float4* __restrict__ inv4, int N) {
  int r = blockIdx.x * 4 + (threadIdx.x >> 6);
  if (r >= N) return;
  int lane = threadIdx.x & 63;
  int beg = ptr[r], end = ptr[r + 1];
  float d0 = 0.f, d1 = 0.f, d2 = 0.f, d3 = 0.f;
  for (int e = beg + lane; e < end; e += 64) {
    float4 es = expS4[pk[e] >> 16];
    d0 += es.x; d1 += es.y; d2 += es.z; d3 += es.w;
  }
#pragma unroll
  for (int o = 32; o > 0; o >>= 1) {
    d0 += __shfl_xor(d0, o, 64); d1 += __shfl_xor(d1, o, 64);
    d2 += __shfl_xor(d2, o, 64); d3 += __shfl_xor(d3, o, 64);
  }
  if (lane == 0) {
    inv4[r] = make_float4(d0 > 0.f ? 1.f / d0 : 0.f,
                          d1 > 0.f ? 1.f / d1 : 0.f,
                          d2 > 0.f ? 1.f / d2 : 0.f,
                          d3 > 0.f ? 1.f / d3 : 0.f);
  }
}

// Edge-parallel weights (exp-free): wt_l[e] = (wE, wR) f32, sequential write.
__global__ void weight_kernel(const int* __restrict__ adj,
                              const unsigned* __restrict__ pk,
                              const float4* __restrict__ expS4,
                              const float4* __restrict__ inv4,
                              uint2* __restrict__ wt0,
                              uint2* __restrict__ wt1, int T) {
  int e = blockIdx.x * blockDim.x + threadIdx.x;
  if (e >= T) return;
  int row = adj[2 * e];
  int rel = (int)(pk[e] >> 16);
  float4 es = expS4[rel];
  float4 iv = inv4[row];
  wt0[e] = make_uint2(__builtin_bit_cast(unsigned, es.x * iv.x),
                      __builtin_bit_cast(unsigned, es.z * iv.z));
  wt1[e] = make_uint2(__builtin_bit_cast(unsigned, es.y * iv.y),
                      __builtin_bit_cast(unsigned, es.w * iv.w));
}

// ---------------------------------------------------------------------------
__global__ __launch_bounds__(256) void agg_fused_kernel(
    const int* __restrict__ ptrE, const int* __restrict__ edgesE,
    const unsigned* __restrict__ ent16, const int* __restrict__ ptrR,
    const int* __restrict__ edgesR, const unsigned* __restrict__ rel16,
    unsigned* __restrict__ fout, int N) {
  int r = blockIdx.x * 4 + (threadIdx.x >> 6);
  if (r >= N) return;
  int lane = threadIdx.x & 63;
  int g = lane >> 4, q = lane & 15;

  float aE[8] = {0, 0, 0, 0, 0, 0, 0, 0};
  float aR[8] = {0, 0, 0, 0, 0, 0, 0, 0};

  auto addh = [&](uint4 u, float* a) {
    h16x2 h0 = __builtin_bit_cast(h16x2, u.x), h1 = __builtin_bit_cast(h16x2, u.y);
    h16x2 h2 = __builtin_bit_cast(h16x2, u.z), h3 = __builtin_bit_cast(h16x2, u.w);
    a[0] += (float)h0.x; a[1] += (float)h0.y;
    a[2] += (float)h1.x; a[3] += (float)h1.y;
    a[4] += (float)h2.x; a[5] += (float)h2.y;
    a[6] += (float)h3.x; a[7] += (float)h3.y;
  };

  int begE = ptrE[r], endE = ptrE[r + 1];
  for (int e0 = begE; e0 < endE; e0 += 8) {
    int eA = e0 + g, eB = e0 + 4 + g;
    if (eA < endE)
      addh(*(const uint4*)(ent16 + (size_t)edgesE[2 * eA + 1] * 64 + 4 * q), aE);
    if (eB < endE)
      addh(*(const uint4*)(ent16 + (size_t)edgesE[2 * eB + 1] * 64 + 4 * q), aE);
  }
  int begR = ptrR[r], endR = ptrR[r + 1];
  for (int e0 = begR; e0 < endR; e0 += 8) {
    int eA = e0 + g, eB = e0 + 4 + g;
    if (eA < endR)
      addh(*(const uint4*)(rel16 + (size_t)edgesR[2 * eA + 1] * 64 + 4 * q), aR);
    if (eB < endR)
      addh(*(const uint4*)(rel16 + (size_t)edgesR[2 * eB + 1] * 64 + 4 * q), aR);
  }
#pragma unroll
  for (int j = 0; j < 8; ++j) {
    aE[j] += __shfl_xor(aE[j], 16, 64); aE[j] += __shfl_xor(aE[j], 32, 64);
    aR[j] += __shfl_xor(aR[j], 16, 64); aR[j] += __shfl_xor(aR[j], 32, 64);
  }
  float sE = (endE > begE) ? 1.f / (float)(endE - begE) : 0.f;
  float sR = (endR > begR) ? 1.f / (float)(endR - begR) : 0.f;
  if (g == 0) {
    float t[8];
#pragma unroll
    for (int j = 0; j < 8; ++j) t[j] = tanh_fast(aE[j] * sE);
    uint4 u;
    u.x = pkhalf2(t[0], t[1]); u.y = pkhalf2(t[2], t[3]);
    u.z = pkhalf2(t[4], t[5]); u.w = pkhalf2(t[6], t[7]);
    *(uint4*)(fout + (size_t)r * 128 + 4 * q) = u;
  } else if (g == 1) {
    float t[8];
#pragma unroll
    for (int j = 0; j < 8; ++j) t[j] = tanh_fast(aR[j] * sR);
    uint4 u;
    u.x = pkhalf2(t[0], t[1]); u.y = pkhalf2(t[2], t[3]);
    u.z = pkhalf2(t[4], t[5]); u.w = pkhalf2(t[6], t[7]);
    *(uint4*)(fout + (size_t)r * 128 + 64 + 4 * q) = u;
  }
}

// ---------------------------------------------------------------------------
// Record-driven fused e+r layer (Round-8 proven form: batch-2, materialized
// sequential weights).
__global__ __launch_bounds__(256) void layer_rec_kernel(
    const int* __restrict__ ptr, const unsigned* __restrict__ pk,
    const uint2* __restrict__ wt, const unsigned* __restrict__ rnorm,
    const unsigned* __restrict__ fin, unsigned* __restrict__ foutE,
    unsigned* __restrict__ foutR, int fstride, int N) {
  int r = blockIdx.x * 4 + (threadIdx.x >> 6);
  if (r >= N) return;
  int lane = threadIdx.x & 63;
  int g = lane >> 4, q = lane & 15;
  int beg = ptr[r], end = ptr[r + 1];

  float aE[8] = {0, 0, 0, 0, 0, 0, 0, 0};
  float aR[8] = {0, 0, 0, 0, 0, 0, 0, 0};

  auto accum = [&](uint4 F, uint4 V, float w, float s, float* a) {
    h16x2 f0 = __builtin_bit_cast(h16x2, F.x), v0 = __builtin_bit_cast(h16x2, V.x);
    h16x2 f1 = __builtin_bit_cast(h16x2, F.y), v1 = __builtin_bit_cast(h16x2, V.y);
    h16x2 f2 = __builtin_bit_cast(h16x2, F.z), v2 = __builtin_bit_cast(h16x2, V.z);
    h16x2 f3 = __builtin_bit_cast(h16x2, F.w), v3 = __builtin_bit_cast(h16x2, V.w);
    a[0] = fmaf((float)f0.x, w, fmaf((float)v0.x, s, a[0]));
    a[1] = fmaf((float)f0.y, w, fmaf((float)v0.y, s, a[1]));
    a[2] = fmaf((float)f1.x, w, fmaf((float)v1.x, s, a[2]));
    a[3] = fmaf((float)f1.y, w, fmaf((float)v1.y, s, a[3]));
    a[4] = fmaf((float)f2.x, w, fmaf((float)v2.x, s, a[4]));
    a[5] = fmaf((float)f2.y, w, fmaf((float)v2.y, s, a[5]));
    a[6] = fmaf((float)f3.x, w, fmaf((float)v3.x, s, a[6]));
    a[7] = fmaf((float)f3.y, w, fmaf((float)v3.y, s, a[7]));
  };

  for (int e0 = beg; e0 < end; e0 += 8) {
    int eA = e0 + g, eB = e0 + 4 + g;
    bool actA = eA < end, actB = eB < end;
    unsigned pkA = actA ? pk[eA] : 0u;
    unsigned pkB = actB ? pk[eB] : 0u;
    uint2 wA = actA ? wt[eA] : make_uint2(0u, 0u);
    uint2 wB = actB ? wt[eB] : make_uint2(0u, 0u);
    int colA = (int)(pkA & 0xFFFFu), relA = (int)(pkA >> 16);
    int colB = (int)(pkB & 0xFFFFu), relB = (int)(pkB >> 16);
    float wAE = bcf(wA.x), wAR = bcf(wA.y);
    float wBE = bcf(wB.x), wBR = bcf(wB.y);

    const unsigned* fA = fin + (size_t)colA * 128;
    const unsigned* fB = fin + (size_t)colB * 128;
    uint4 EA = *(const uint4*)(fA + 4 * q);
    uint4 RA = *(const uint4*)(fA + 64 + 4 * q);
    uint4 VA = *(const uint4*)(rnorm + (size_t)relA * 64 + 4 * q);
    uint4 EB = *(const uint4*)(fB + 4 * q);
    uint4 RB = *(const uint4*)(fB + 64 + 4 * q);
    uint4 VB = *(const uint4*)(rnorm + (size_t)relB * 64 + 4 * q);

    float dAE = dot8(EA, VA), dAR = dot8(RA, VA);
    float dBE = dot8(EB, VB), dBR = dot8(RB, VB);
#pragma unroll
    for (int m = 1; m < 16; m <<= 1) {
      dAE += __shfl_xor(dAE, m, 64);
      dAR += __shfl_xor(dAR, m, 64);
      dBE += __shfl_xor(dBE, m, 64);
      dBR += __shfl_xor(dBR, m, 64);
    }
    float sAE = -2.f * wAE * dAE, sAR = -2.f * wAR * dAR;
    float sBE = -2.f * wBE * dBE, sBR = -2.f * wBR * dBR;
    accum(EA, VA, wAE, sAE, aE);
    accum(RA, VA, wAR, sAR, aR);
    accum(EB, VB, wBE, sBE, aE);
    accum(RB, VB, wBR, sBR, aR);
  }

#pragma unroll
  for (int j = 0; j < 8; ++j) {
    aE[j] += __shfl_xor(aE[j], 16, 64); aE[j] += __shfl_xor(aE[j], 32, 64);
    aR[j] += __shfl_xor(aR[j], 16, 64); aR[j] += __shfl_xor(aR[j], 32, 64);
  }
  if (g == 0) {
    float t[8];
#pragma unroll
    for (int j = 0; j < 8; ++j) t[j] = tanh_fast(aE[j]);
    uint4 u;
    u.x = pkhalf2(t[0], t[1]); u.y = pkhalf2(t[2], t[3]);
    u.z = pkhalf2(t[4], t[5]); u.w = pkhalf2(t[6], t[7]);
    *(uint4*)(foutE + (size_t)r * fstride + 4 * q) = u;
  } else if (g == 1) {
    float t[8];
#pragma unroll
    for (int j = 0; j < 8; ++j) t[j] = tanh_fast(aR[j]);
    uint4 u;
    u.x = pkhalf2(t[0], t[1]); u.y = pkhalf2(t[2], t[3]);
    u.z = pkhalf2(t[4], t[5]); u.w = pkhalf2(t[6], t[7]);
    *(uint4*)(foutR + (size_t)r * fstride + 4 * q) = u;
  }
}

// ---------------------------------------------------------------------------
// Pack B matrices into f16 MFMA 32x32x16 fragment order.
__device__ __forceinline__ void pack_one32(const float* __restrict__ src,
                                           unsigned short* __restrict__ dst,
                                           int NT, int srcld, int mode, int f,
                                           int lane) {
  int kt = f / NT, nt = f % NT;
  int kbase = 16 * kt + 8 * (lane >> 5);
  int n = 32 * nt + (lane & 31);
  unsigned short tmp[8];
#pragma unroll
  for (int j = 0; j < 8; ++j) {
    int k = kbase + j;
    float v = (mode == 0) ? src[(size_t)k * srcld + n] : src[(size_t)n * srcld + k];
    tmp[j] = f2h(v);
  }
  *(uint4*)(dst + ((size_t)f * 64 + lane) * 8) = *(uint4*)tmp;
}
__global__ void pack_all_kernel(const float* eP, const float* eG,
                                const float* rP, const float* rG,
                                unsigned short* b1e, unsigned short* b2e,
                                unsigned short* b3e, unsigned short* b1r,
                                unsigned short* b2r, unsigned short* b3r) {
  int f = blockIdx.x * 4 + (threadIdx.x >> 6);
  int lane = threadIdx.x & 63;
  if (f < 48)       pack_one32(eP, b1e, 2, 384, 1, f, lane);
  else if (f < 96)  pack_one32(eP, b2e, 12, 384, 0, f - 48, lane);
  else if (f < 384) pack_one32(eG, b3e, 12, 384, 0, f - 96, lane);
  else if (f < 432) pack_one32(rP, b1r, 2, 384, 1, f - 384, lane);
  else if (f < 480) pack_one32(rP, b2r, 12, 384, 0, f - 432, lane);
  else if (f < 768) pack_one32(rG, b3r, 12, 384, 0, f - 480, lane);
}

// ---------------------------------------------------------------------------
// Fused proxy/gate epilogue: both sides in one dispatch (side = blockIdx&1).
// 32 rows/block, 256 threads (4 waves), f16 MFMA 32x32x16. (Round-9 exact.)
// C/D layout: col = lane&31, row = (reg&3) + 8*(reg>>2) + 4*(lane>>5).
__global__ __launch_bounds__(256) void final_fused_kernel(
    const unsigned* __restrict__ f0, const unsigned* __restrict__ f1,
    const unsigned* __restrict__ outu,
    const unsigned short* __restrict__ B1e, const unsigned short* __restrict__ B2e,
    const unsigned short* __restrict__ B3e, const unsigned short* __restrict__ B1r,
    const unsigned short* __restrict__ B2r, const unsigned short* __restrict__ B3r,
    const float* __restrict__ biasE, const float* __restrict__ biasR,
    float* __restrict__ gout) {
  __shared__ __align__(16) unsigned sOutH[32][204];   // fp16 pairs (192 used)
  __shared__ __align__(16) float sPa[32][68];
  __shared__ __align__(16) unsigned short sPaH[32][72];
  __shared__ float sInv[32];
  unsigned short* sOutHs = (unsigned short*)&sOutH[0][0];  // row stride 408

  const int side = blockIdx.x & 1;
  const int row0 = (blockIdx.x >> 1) * 32;
  const int plane = side ? 64 : 0;
  const unsigned* f2 = outu + (side ? 704 : 0);
  const unsigned short* B1 = side ? B1r : B1e;
  const unsigned short* B2 = side ? B2r : B2e;
  const unsigned short* B3 = side ? B3r : B3e;
  const float* bias = side ? biasR : biasE;
  const int coloff = side ? 384 : 0;

  const int t = threadIdx.x;
  const int w = t >> 6, lane = t & 63;
  const int l31 = lane & 31, l5 = lane >> 5;

  // 1. load outputs planes + fused row sumsq (8 threads per row)
  {
    int rloc = t >> 3;      // 0..31
    int c0 = t & 7;
    int rg = row0 + rloc;
    float ss = 0.f;
#pragma unroll
    for (int i = 0; i < 6; ++i) {
      int c = c0 + 8 * i;   // 0..47
      int buf = c >> 4, j = c & 15;
      const unsigned* src;
      if (buf == 0)      src = f0 + (size_t)rg * 128 + plane + 4 * j;
      else if (buf == 1) src = f1 + (size_t)rg * 128 + plane + 4 * j;
      else               src = f2 + (size_t)rg * 768 + 4 * j;
      uint4 u = *(const uint4*)src;
      *(uint4*)&sOutH[rloc][c * 4] = u;
      ss = fdot2u(u.x, u.x, fdot2u(u.y, u.y,
           fdot2u(u.z, u.z, fdot2u(u.w, u.w, ss))));
    }
    ss += __shfl_xor(ss, 1, 64);
    ss += __shfl_xor(ss, 2, 64);
    ss += __shfl_xor(ss, 4, 64);
    if (c0 == 0) sInv[rloc] = 1.f / fmaxf(sqrtf(ss), 1e-12f);
  }
  __syncthreads();

  // 2. GEMM1: S = outputs @ proxyT (waves 0,1; ct = w)
  if (w < 2) {
    int ct = w;
    f32x16 acc = {0.f, 0.f, 0.f, 0.f, 0.f, 0.f, 0.f, 0.f,
                  0.f, 0.f, 0.f, 0.f, 0.f, 0.f, 0.f, 0.f};
#pragma unroll
    for (int kt = 0; kt < 24; ++kt) {
      f16x8 a = __builtin_bit_cast(
          f16x8, *(const uint4*)&sOutH[l31][8 * kt + 4 * l5]);
      f16x8 b = *(const f16x8*)(B1 + ((size_t)(kt * 2 + ct) * 64 + lane) * 8);
      acc = __builtin_amdgcn_mfma_f32_32x32x16_f16(a, b, acc, 0, 0, 0);
    }
#pragma unroll
    for (int reg = 0; reg < 16; ++reg) {
      int row = (reg & 3) + 8 * (reg >> 2) + 4 * l5;
      sPa[row][ct * 32 + l31] = acc[reg] * sInv[row];
    }
  }
  __syncthreads();

  // 3. softmax over 64 proxies (8 rows/wave) -> f16 pa
  for (int rr = 8 * w; rr < 8 * w + 8; ++rr) {
    float v = sPa[rr][lane];
    float mx = wave_max(v);
    float e = __expf(v - mx);
    float s = wave_sum(e);
    sPaH[rr][lane] = f2h(e / s);
  }
  __syncthreads();

  // 4. GEMM2: pf = outputs - pa @ proxy; overwrite sOutH with pf,
  //    stash outputs bits in regs. wave w -> strips 3w..3w+2
  const int ntb = 3 * w;
  unsigned outv[3][8];
  {
    f32x16 acc2[3];
#pragma unroll
    for (int s = 0; s < 3; ++s)
#pragma unroll
      for (int i = 0; i < 16; ++i) acc2[s][i] = 0.f;
#pragma unroll
    for (int kt = 0; kt < 4; ++kt) {
      f16x8 a = __builtin_bit_cast(
          f16x8, *(const uint4*)&sPaH[l31][16 * kt + 8 * l5]);
#pragma unroll
      for (int s = 0; s < 3; ++s) {
        f16x8 b = *(const f16x8*)(B2 + ((size_t)(kt * 12 + ntb + s) * 64 + lane) * 8);
        acc2[s] = __builtin_amdgcn_mfma_f32_32x32x16_f16(a, b, acc2[s], 0, 0, 0);
      }
    }
#pragma unroll
    for (int s = 0; s < 3; ++s) {
      int col = 32 * (ntb + s) + l31;
#pragma unroll
      for (int p = 0; p < 8; ++p) {
        int ra = ((2 * p) & 3) + 8 * (p >> 1) + 4 * l5;
        unsigned short u0 = sOutHs[ra * 408 + col];
        unsigned short u1 = sOutHs[(ra + 1) * 408 + col];
        outv[s][p] = (unsigned)u0 | ((unsigned)u1 << 16);
        float pf0 = h2f(u0) - acc2[s][2 * p];
        float pf1 = h2f(u1) - acc2[s][2 * p + 1];
        sOutHs[ra * 408 + col] = f2h(pf0);
        sOutHs[(ra + 1) * 408 + col] = f2h(pf1);
      }
    }
  }
  __syncthreads();

  // 5. GEMM3: gate logits = pf @ gateK (kt-outer, A reused across 3 strips)
  f32x16 acc3[3];
#pragma unroll
  for (int s = 0; s < 3; ++s)
#pragma unroll
    for (int i = 0; i < 16; ++i) acc3[s][i] = 0.f;
#pragma unroll
  for (int kt = 0; kt < 24; ++kt) {
    f16x8 a = __builtin_bit_cast(
        f16x8, *(const uint4*)&sOutH[l31][8 * kt + 4 * l5]);
#pragma unroll
    for (int s = 0; s < 3; ++s) {
      f16x8 b = *(const f16x8*)(B3 + ((size_t)(kt * 12 + ntb + s) * 64 + lane) * 8);
      acc3[s] = __builtin_amdgcn_mfma_f32_32x32x16_f16(a, b, acc3[s], 0, 0, 0);
    }
  }

  // 6. sigmoid gate + combine + store
#pragma unroll
  for (int s = 0; s < 3; ++s) {
    int col = 32 * (ntb + s) + l31;
    float bv = bias[col];
#pragma unroll
    for (int p = 0; p < 8; ++p) {
      int ra = ((2 * p) & 3) + 8 * (p >> 1) + 4 * l5;
      float g0 = 1.f / (1.f + __expf(-(acc3[s][2 * p] + bv)));
      float g1 = 1.f / (1.f + __expf(-(acc3[s][2 * p + 1] + bv)));
      float pf0 = h2f(sOutHs[ra * 408 + col]);
      float pf1 = h2f(sOutHs[(ra + 1) * 408 + col]);
      unsigned ov = outv[s][p];
      float o0 = h2f((unsigned short)(ov & 0xffffu));
      float o1 = h2f((unsigned short)(ov >> 16));
      gout[(size_t)(row0 + ra) * 768 + coloff + col] = g0 * o0 + (1.f - g0) * pf0;
      gout[(size_t)(row0 + ra + 1) * 768 + coloff + col] =
          g1 * o1 + (1.f - g1) * pf1;
    }
  }
}

extern "C" void kernel_launch(void* const* d_in, const int* in_sizes, int n_in,
                              void* d_out, int out_size, void* d_ws,
                              size_t ws_size, hipStream_t stream) {
  (void)n_in; (void)out_size; (void)ws_size;
  const float* ent_emb = (const float*)d_in[0];
  const float* rel_emb = (const float*)d_in[1];
  const float* e_gate  = (const float*)d_in[2];
  const float* e_proxy = (const float*)d_in[3];
  const float* e_bias  = (const float*)d_in[4];
  const float* e_attn  = (const float*)d_in[5];
  const float* r_gate  = (const float*)d_in[6];
  const float* r_proxy = (const float*)d_in[7];
  const float* r_bias  = (const float*)d_in[8];
  const float* r_attn  = (const float*)d_in[9];
  const int* adj   = (const int*)d_in[11];
  const int* idx   = (const int*)d_in[12];
  const int* ent_m = (const int*)d_in[13];
  const int* rel_m = (const int*)d_in[14];
  const int N = in_sizes[0] / 128;
  const int R = in_sizes[1] / 128;
  const int T = in_sizes[10];
  float* out = (float*)d_out;

  char* w = (char*)d_ws;
  size_t used = 0;
  auto alloc = [&](size_t bytes) {
    void* p = (void*)(w + used);
    used += (bytes + 255) & ~(size_t)255;
    return p;
  };
  int* ptr_adj  = (int*)alloc((size_t)(N + 1) * sizeof(int));
  int* ptr_ent  = (int*)alloc((size_t)(N + 1) * sizeof(int));
  int* ptr_rel  = (int*)alloc((size_t)(N + 1) * sizeof(int));
  unsigned short* b1e = (unsigned short*)alloc(48 * 1024);
  unsigned short* b2e = (unsigned short*)alloc(48 * 1024);
  unsigned short* b3e = (unsigned short*)alloc(288 * 1024);
  unsigned short* b1r = (unsigned short*)alloc(48 * 1024);
  unsigned short* b2r = (unsigned short*)alloc(48 * 1024);
  unsigned short* b3r = (unsigned short*)alloc(288 * 1024);
  unsigned* rnorm = (unsigned*)alloc((size_t)R * 64 * 4);
  unsigned* rel16 = (unsigned*)alloc((size_t)R * 64 * 4);
  unsigned* ent16 = (unsigned*)alloc((size_t)N * 64 * 4);
  unsigned* fsrc0 = (unsigned*)alloc((size_t)N * 128 * 4);
  unsigned* fsrc1 = (unsigned*)alloc((size_t)N * 128 * 4);
  float4* expS4 = (float4*)alloc((size_t)R * 16);
  float4* inv4  = (float4*)alloc((size_t)N * 16);
  unsigned* pk = (unsigned*)alloc((size_t)T * 4);
  uint2* wt0 = (uint2*)alloc((size_t)T * 8);
  uint2* wt1 = (uint2*)alloc((size_t)T * 8);

  dim3 b256(256);
  rowptr3_kernel<<<(3 * (N + 1) + 255) / 256, b256, 0, stream>>>(
      adj, ent_m, rel_m, T, N, ptr_adj, ptr_ent, ptr_rel);
  relprep_kernel<<<(R + 3) / 4, b256, 0, stream>>>(rel_emb, e_attn, r_attn, R,
                                                   expS4, rnorm, rel16);
  pack_f16_kernel<<<(N * 64 + 255) / 256, b256, 0, stream>>>(ent_emb, ent16,
                                                             N * 64);
  pack_edges_kernel<<<(T + 255) / 256, b256, 0, stream>>>(adj, idx, pk, T);
  pack_all_kernel<<<192, b256, 0, stream>>>(e_proxy, e_gate, r_proxy, r_gate,
                                            b1e, b2e, b3e, b1r, b2r, b3r);

  int grow = (N + 3) / 4;
  stats4_kernel<<<grow, b256, 0, stream>>>(ptr_adj, pk, expS4, inv4, N);
  weight_kernel<<<(T + 255) / 256, b256, 0, stream>>>(adj, pk, expS4, inv4,
                                                      wt0, wt1, T);
  agg_fused_kernel<<<grow, b256, 0, stream>>>(ptr_ent, ent_m, ent16, ptr_rel,
                                              rel_m, rel16, fsrc0, N);
  // layer0: fsrc0 -> fsrc1 ; layer1: -> scratch planes at row ends of d_out
  unsigned* outu = (unsigned*)out;
  layer_rec_kernel<<<grow, b256, 0, stream>>>(ptr_adj, pk, wt0, rnorm, fsrc0,
                                              fsrc1, fsrc1 + 64, 128, N);
  layer_rec_kernel<<<grow, b256, 0, stream>>>(ptr_adj, pk, wt1, rnorm, fsrc1,
                                              outu, outu + 704, 768, N);

  // fused finals: both sides in one dispatch (race-free by plane layout)
  int fblocks = 2 * ((N + 31) / 32);
  final_fused_kernel<<<fblocks, b256, 0, stream>>>(
      fsrc0, fsrc1, outu, b1e, b2e, b3e, b1r, b2r, b3r, e_bias, r_bias, out);
}